// Round 3
// baseline (697.991 us; speedup 1.0000x reference)
//
#include <hip/hip_runtime.h>
#include <stdint.h>
#include <stddef.h>

#define T_ 4
#define B_ 64
#define L_ 64
#define D_ 768
#define H_ 3072
#define M1_ 16384      // T*B*L rows
#define BLD_ 3145728   // B*L*D
#define NW_ 2359296    // 3072*768
#define HL_ 196608     // H_*L_

using short8 = __attribute__((ext_vector_type(8))) short;
using f32x4  = __attribute__((ext_vector_type(4))) float;
using f4     = __attribute__((ext_vector_type(4))) float;
using us4    = __attribute__((ext_vector_type(4))) unsigned short;
using int4v  = __attribute__((ext_vector_type(4))) int;
using uc4    = __attribute__((ext_vector_type(4))) unsigned char;

static __device__ __forceinline__ unsigned short f2bf(float f) {
  uint32_t u = __float_as_uint(f);
  uint32_t r = (u + 0x7FFFu + ((u >> 16) & 1u)) >> 16;   // RNE
  return (unsigned short)r;
}
static __device__ __forceinline__ float bf2f(unsigned short b) {
  return __uint_as_float(((uint32_t)b) << 16);
}
static __device__ __forceinline__ void gload_lds16(const void* g, void* l) {
  __builtin_amdgcn_global_load_lds((const __attribute__((address_space(1))) void*)g,
                                   (__attribute__((address_space(3))) void*)l, 16, 0, 0);
}

// ---- weight conversion: W1 -> 4 signed-byte planes of round(w*2^33); W2 -> bf16 hi+lo ----
__global__ __launch_bounds__(256) void k_convert(
    const float* __restrict__ W1, const float* __restrict__ W2,
    signed char* __restrict__ Q0, signed char* __restrict__ Q1,
    signed char* __restrict__ Q2, signed char* __restrict__ Q3,
    unsigned short* __restrict__ W2h, unsigned short* __restrict__ W2l) {
  int i = blockIdx.x * 256 + threadIdx.x;
  if (i >= NW_) return;
  double w = (double)W1[i];
  long long q = llrint(w * 8589934592.0);                 // w * 2^33
  if (q >  2147483647LL) q =  2147483647LL;
  if (q < -2147483647LL) q = -2147483647LL;
  int ii = (int)q;
  int b0 = ((ii + 128) & 255) - 128; ii = (ii - b0) / 256;
  int b1 = ((ii + 128) & 255) - 128; ii = (ii - b1) / 256;
  int b2 = ((ii + 128) & 255) - 128; ii = (ii - b2) / 256;
  Q0[i] = (signed char)b0; Q1[i] = (signed char)b1;
  Q2[i] = (signed char)b2; Q3[i] = (signed char)ii;
  float w2 = W2[i];
  unsigned short h = f2bf(w2);
  W2h[i] = h;
  W2l[i] = f2bf(w2 - bf2f(h));
}

// ---- LIF1 in fp64 (matches high-precision reference), spikes as i8 {0,1} ----
__global__ __launch_bounds__(256) void k_lif1(const float* __restrict__ x,
                                              unsigned char* __restrict__ s1) {
  size_t i = ((size_t)blockIdx.x * 256 + threadIdx.x) * 4;
  double v0 = 0., v1 = 0., v2 = 0., v3 = 0.;
  #pragma unroll
  for (int t = 0; t < T_; ++t) {
    f4 xt = *(const f4*)(x + (size_t)t * BLD_ + i);
    v0 = v0 + ((double)xt.x - v0) * 0.5;
    v1 = v1 + ((double)xt.y - v1) * 0.5;
    v2 = v2 + ((double)xt.z - v2) * 0.5;
    v3 = v3 + ((double)xt.w - v3) * 0.5;
    uc4 s;
    s.x = (v0 >= 1.0) ? 1 : 0;
    s.y = (v1 >= 1.0) ? 1 : 0;
    s.z = (v2 >= 1.0) ? 1 : 0;
    s.w = (v3 >= 1.0) ? 1 : 0;
    *(uc4*)(s1 + (size_t)t * BLD_ + i) = s;
    v0 = s.x ? 0. : v0;
    v1 = s.y ? 0. : v1;
    v2 = s.z ? 0. : v2;
    v3 = s.w ? 0. : v3;
  }
}

// ---- exact integer GEMM1: h = (sum_k s*q)*2^-33, 4 byte planes ----
// block 256 thr = 4 waves (2x2), tile 128m x 64n, BK=64.
// MODE 1: fp64 column stats only (grid.y: contiguous 128-row m-tiles)
// MODE 2: BN1-apply (fp64) + fp64 LIF2 + transposed bf16 spike write
//         (grid.y: bl-chunks, rows m = t*4096 + by*32 + j)
template <int MODE>
__global__ __launch_bounds__(256) void k_gemm1(
    const unsigned char* __restrict__ A,
    const signed char* __restrict__ Q0, const signed char* __restrict__ Q1,
    const signed char* __restrict__ Q2, const signed char* __restrict__ Q3,
    double* __restrict__ sumD, double* __restrict__ sqD,
    const double* __restrict__ mean, const double* __restrict__ rstd,
    const float* __restrict__ gamma, const float* __restrict__ beta,
    unsigned short* __restrict__ s2) {
  constexpr int SMEM_BYTES = (MODE == 2) ? 65536 : 24576;
  __shared__ __align__(16) char smem[SMEM_BYTES];
  signed char* ldsA = (signed char*)smem;          // [128][64] i8
  signed char* ldsB = (signed char*)smem + 8192;   // 4 planes x [64][64] i8

  const int tid  = threadIdx.x;
  const int lane = tid & 63;
  const int w    = tid >> 6;
  const int wr = tid >> 7;            // wave m (0,1)
  const int wc = (tid >> 6) & 1;      // wave n (0,1)
  const int n0 = blockIdx.x * 64;
  const int by = blockIdx.y;

  // staging maps
  const int aIdx0 = w * 128 + lane;             // +64 for j=1
  const int aRowL0 = aIdx0 >> 2;
  const int aRowL1 = (aIdx0 + 64) >> 2;
  auto grow = [&](int r) -> size_t {
    if (MODE == 2) return (size_t)4096 * (r >> 5) + (size_t)by * 32 + (r & 31);
    return (size_t)by * 128 + r;
  };
  const unsigned char* Ag0 = A + grow(aRowL0) * 768 + (aIdx0 & 3) * 16;
  const unsigned char* Ag1 = A + grow(aRowL1) * 768 + ((aIdx0 + 64) & 3) * 16;
  const int bIdx = w * 64 + lane;
  const int bRow = bIdx >> 2;
  const int bCol16 = (bIdx & 3) * 16;
  const signed char* Bg[4];
  Bg[0] = Q0 + (size_t)(n0 + bRow) * 768 + bCol16;
  Bg[1] = Q1 + (size_t)(n0 + bRow) * 768 + bCol16;
  Bg[2] = Q2 + (size_t)(n0 + bRow) * 768 + bCol16;
  Bg[3] = Q3 + (size_t)(n0 + bRow) * 768 + bCol16;

  int4v acc[4][4][2] = {};   // [plane][m][n]

  const int arow = wr * 64 + (lane & 15);
  const int kb = (lane >> 4) * 16;

  for (int k0 = 0; k0 < 768; k0 += 64) {
    gload_lds16(Ag0 + k0, ldsA + aIdx0 * 16);
    gload_lds16(Ag1 + k0, ldsA + (aIdx0 + 64) * 16);
    #pragma unroll
    for (int p = 0; p < 4; ++p)
      gload_lds16(Bg[p] + k0, ldsB + p * 4096 + bIdx * 16);
    __syncthreads();
    int4v av[4], bv[2][4];
    #pragma unroll
    for (int m = 0; m < 4; ++m)
      av[m] = *(const int4v*)(ldsA + (arow + m * 16) * 64 + kb);
    #pragma unroll
    for (int n = 0; n < 2; ++n)
      #pragma unroll
      for (int p = 0; p < 4; ++p)
        bv[n][p] = *(const int4v*)(ldsB + p * 4096 + (wc * 32 + n * 16 + (lane & 15)) * 64 + kb);
    #pragma unroll
    for (int p = 0; p < 4; ++p)
      #pragma unroll
      for (int m = 0; m < 4; ++m)
        #pragma unroll
        for (int n = 0; n < 2; ++n)
          acc[p][m][n] = __builtin_amdgcn_mfma_i32_16x16x64_i8(av[m], bv[n][p], acc[p][m][n], 0, 0, 0);
    __syncthreads();
  }

  auto H64 = [&](int m, int n, int r) -> double {
    long long v = ((long long)acc[3][m][n][r] << 24) + ((long long)acc[2][m][n][r] << 16)
                + ((long long)acc[1][m][n][r] << 8) + (long long)acc[0][m][n][r];
    return (double)v * (1.0 / 8589934592.0);
  };

  if constexpr (MODE == 1) {
    #pragma unroll
    for (int n = 0; n < 2; ++n) {
      double s = 0.0, q = 0.0;
      #pragma unroll
      for (int m = 0; m < 4; ++m)
        #pragma unroll
        for (int r = 0; r < 4; ++r) {
          double v = H64(m, n, r);
          s += v;
          q += v * v;
        }
      s += __shfl_xor(s, 16);
      q += __shfl_xor(q, 16);
      s += __shfl_xor(s, 32);
      q += __shfl_xor(q, 32);
      if ((lane >> 4) == 0) {
        int col = n0 + wc * 32 + n * 16 + lane;
        atomicAdd(&sumD[col], s);
        atomicAdd(&sqD[col], q);
      }
    }
  }

  if constexpr (MODE == 2) {
    double* smE = (double*)smem;   // [128][64] fp64 g-values
    double mn[2], rs[2], gm[2], bt[2];
    #pragma unroll
    for (int n = 0; n < 2; ++n) {
      int c = n0 + wc * 32 + n * 16 + (lane & 15);
      mn[n] = mean[c]; rs[n] = rstd[c];
      gm[n] = (double)gamma[c]; bt[n] = (double)beta[c];
    }
    #pragma unroll
    for (int m = 0; m < 4; ++m)
      #pragma unroll
      for (int n = 0; n < 2; ++n)
        #pragma unroll
        for (int r = 0; r < 4; ++r) {
          int row = wr * 64 + m * 16 + ((lane >> 4) << 2) + r;
          int col = wc * 32 + n * 16 + (lane & 15);
          smE[row * 64 + col] = (H64(m, n, r) - mn[n]) * rs[n] * gm[n] + bt[n];
        }
    __syncthreads();
    // fp64 LIF chains over t; spikes written in the reference's (T*B, H, L) layout
    const int bI = by >> 1;
    const int l0 = (by & 1) * 32;
    const int j0 = (tid & 7) * 4;
    #pragma unroll
    for (int it = 0; it < 2; ++it) {
      const int hl = (tid >> 3) + it * 32;
      const size_t hg = (size_t)(n0 + hl);
      unsigned short sp[4][4];   // [t][jj]
      #pragma unroll
      for (int jj = 0; jj < 4; ++jj) {
        double v = 0.;
        #pragma unroll
        for (int t = 0; t < 4; ++t) {
          double g = smE[(t * 32 + j0 + jj) * 64 + hl];
          v = v + (g - v) * 0.5;
          bool s = (v >= 1.0);
          sp[t][jj] = s ? (unsigned short)0x3F80 : (unsigned short)0;
          v = s ? 0. : v;
        }
      }
      #pragma unroll
      for (int t = 0; t < 4; ++t) {
        us4 wv;
        wv.x = sp[t][0]; wv.y = sp[t][1]; wv.z = sp[t][2]; wv.w = sp[t][3];
        *(us4*)(s2 + (size_t)(t * 64 + bI) * HL_ + hg * 64 + l0 + j0) = wv;
      }
    }
  }
}

// ---- GEMM2: bf16 split, C store + fp64 column stats ----
__global__ __launch_bounds__(256) void k_gemm2(
    const unsigned short* __restrict__ A,
    const unsigned short* __restrict__ Bh,
    const unsigned short* __restrict__ Bl,
    float* __restrict__ C,
    double* __restrict__ sumD, double* __restrict__ sqD) {
  __shared__ __align__(16) unsigned short lds[3 * 8192];
  const int tid = threadIdx.x;
  const int lane = tid & 63;
  const int wr = tid >> 7;
  const int wc = (tid >> 6) & 1;
  const int n0 = blockIdx.x * 128;
  const int by = blockIdx.y;
  const int K = H_, N = D_;

  unsigned short* ldsA = lds;
  unsigned short* ldsB = lds + 8192;
  unsigned short* ldsC = lds + 16384;

  const int srow = tid >> 3;
  const int scol = (tid & 7) * 8;
  const unsigned short* Ag  = A  + (size_t)(by * 128 + srow) * K + scol;
  const unsigned short* Bhg = Bh + (size_t)(n0 + srow) * K + scol;
  const unsigned short* Blg = Bl + (size_t)(n0 + srow) * K + scol;

  f32x4 acc[4][4] = {};
  const int arow = wr * 64 + (lane & 15);
  const int brow = wc * 64 + (lane & 15);
  const int koff = (lane >> 4) * 8;

  for (int k0 = 0; k0 < K; k0 += 64) {
    #pragma unroll
    for (int i = 0; i < 4; ++i) {
      gload_lds16(Ag + (size_t)(i * 32) * K + k0, ldsA + i * 2048 + tid * 8);
      gload_lds16(Bhg + (size_t)(i * 32) * K + k0, ldsB + i * 2048 + tid * 8);
      gload_lds16(Blg + (size_t)(i * 32) * K + k0, ldsC + i * 2048 + tid * 8);
    }
    __syncthreads();
    #pragma unroll
    for (int kk = 0; kk < 64; kk += 32) {
      short8 av[4], bv[4], cv[4];
      #pragma unroll
      for (int m = 0; m < 4; ++m)
        av[m] = *(const short8*)(ldsA + (arow + m * 16) * 64 + kk + koff);
      #pragma unroll
      for (int n = 0; n < 4; ++n) {
        bv[n] = *(const short8*)(ldsB + (brow + n * 16) * 64 + kk + koff);
        cv[n] = *(const short8*)(ldsC + (brow + n * 16) * 64 + kk + koff);
      }
      #pragma unroll
      for (int m = 0; m < 4; ++m)
        #pragma unroll
        for (int n = 0; n < 4; ++n) {
          acc[m][n] = __builtin_amdgcn_mfma_f32_16x16x32_bf16(av[m], bv[n], acc[m][n], 0, 0, 0);
          acc[m][n] = __builtin_amdgcn_mfma_f32_16x16x32_bf16(av[m], cv[n], acc[m][n], 0, 0, 0);
        }
    }
    __syncthreads();
  }

  #pragma unroll
  for (int n = 0; n < 4; ++n) {
    double s = 0.0, q = 0.0;
    #pragma unroll
    for (int m = 0; m < 4; ++m)
      #pragma unroll
      for (int r = 0; r < 4; ++r) {
        float v = acc[m][n][r];
        s += (double)v;
        q += (double)v * (double)v;
      }
    s += __shfl_xor(s, 16);
    q += __shfl_xor(q, 16);
    s += __shfl_xor(s, 32);
    q += __shfl_xor(q, 32);
    if ((lane >> 4) == 0) {
      int col = n0 + wc * 64 + n * 16 + lane;
      atomicAdd(&sumD[col], s);
      atomicAdd(&sqD[col], q);
    }
  }
  const int r0 = by * 128 + wr * 64 + ((lane >> 4) << 2);
  const int c0 = n0 + wc * 64 + (lane & 15);
  #pragma unroll
  for (int m = 0; m < 4; ++m)
    #pragma unroll
    for (int n = 0; n < 4; ++n)
      #pragma unroll
      for (int r = 0; r < 4; ++r)
        C[(size_t)(r0 + m * 16 + r) * N + (c0 + n * 16)] = acc[m][n][r];
}

// ---- BN finalize (fp64) ----
__global__ __launch_bounds__(256) void k_bnfinal(
    const double* __restrict__ sum, const double* __restrict__ sq,
    double* __restrict__ mean, double* __restrict__ rstd, int N, double invM) {
  int i = blockIdx.x * 256 + threadIdx.x;
  if (i >= N) return;
  double m = sum[i] * invM;
  double v = sq[i] * invM - m * m;
  mean[i] = m;
  rstd[i] = 1.0 / sqrt(v + 1e-5);
}

// ---- BN2-apply (fp64) + (L,D)->(D,L) per-tb transpose -> fp32 out ----
__global__ __launch_bounds__(256) void k_bn2apply(
    const float* __restrict__ O, const double* __restrict__ mean,
    const double* __restrict__ rstd, const float* __restrict__ gamma,
    const float* __restrict__ beta, float* __restrict__ out) {
  __shared__ __align__(16) float sm[64 * 65];
  const int tid = threadIdx.x;
  const int d0 = blockIdx.x * 64;
  const int tb = blockIdx.y;
  const int doff = tid & 63;
  const int lgrp = tid >> 6;
  const double mn = mean[d0 + doff];
  const double rs = rstd[d0 + doff];
  const double gm = (double)gamma[d0 + doff];
  const double bt = (double)beta[d0 + doff];
  #pragma unroll 4
  for (int p = 0; p < 16; ++p) {
    const int l = p * 4 + lgrp;
    double v = (double)O[((size_t)tb * 64 + l) * D_ + d0 + doff];
    sm[doff * 65 + l] = (float)(((v - mn) * rs) * gm + bt);
  }
  __syncthreads();
  const int l4 = (tid & 15) * 4;
  const int db = tid >> 4;
  #pragma unroll
  for (int p = 0; p < 4; ++p) {
    const int dd = p * 16 + db;
    f4 w;
    w.x = sm[dd * 65 + l4 + 0];
    w.y = sm[dd * 65 + l4 + 1];
    w.z = sm[dd * 65 + l4 + 2];
    w.w = sm[dd * 65 + l4 + 3];
    *(f4*)(out + (size_t)tb * (D_ * L_) + (size_t)(d0 + dd) * 64 + l4) = w;
  }
}

extern "C" void kernel_launch(void* const* d_in, const int* in_sizes, int n_in,
                              void* d_out, int out_size, void* d_ws, size_t ws_size,
                              hipStream_t stream) {
  const float* x      = (const float*)d_in[0];
  const float* W1     = (const float*)d_in[1];
  const float* gamma1 = (const float*)d_in[2];
  const float* beta1  = (const float*)d_in[3];
  const float* W2     = (const float*)d_in[4];
  const float* gamma2 = (const float*)d_in[5];
  const float* beta2  = (const float*)d_in[6];
  float* out = (float*)d_out;
  (void)in_sizes; (void)n_in; (void)out_size; (void)ws_size;

  // s1 (i8 spikes, 12.6 MB) lives in d_out; d_out is fully rewritten at the end.
  unsigned char* s1 = (unsigned char*)d_out;

  char* ws = (char*)d_ws;
  size_t off = 0;
  auto alloc = [&](size_t bytes) -> void* {
    void* p = ws + off;
    off += (bytes + 255) & ~(size_t)255;
    return p;
  };
  signed char* Q0 = (signed char*)alloc(NW_);
  signed char* Q1 = (signed char*)alloc(NW_);
  signed char* Q2 = (signed char*)alloc(NW_);
  signed char* Q3 = (signed char*)alloc(NW_);
  unsigned short* W2h = (unsigned short*)alloc((size_t)NW_ * 2);
  unsigned short* W2l = (unsigned short*)alloc((size_t)NW_ * 2);
  unsigned short* s2  = (unsigned short*)alloc((size_t)M1_ * H_ * 2);   // 100.7 MB
  float* O2           = (float*)alloc((size_t)M1_ * D_ * 4);            // 50.3 MB
  double* stats       = (double*)alloc((size_t)(2 * H_ + 2 * D_) * 8);
  double* bn1s = stats;
  double* bn1q = stats + H_;
  double* bn2s = stats + 2 * H_;
  double* bn2q = stats + 2 * H_ + D_;
  double* mean1 = (double*)alloc((size_t)H_ * 8);
  double* rstd1 = (double*)alloc((size_t)H_ * 8);
  double* mean2 = (double*)alloc((size_t)D_ * 8);
  double* rstd2 = (double*)alloc((size_t)D_ * 8);

  hipMemsetAsync(stats, 0, (size_t)(2 * H_ + 2 * D_) * 8, stream);
  k_convert<<<NW_ / 256, 256, 0, stream>>>(W1, W2, Q0, Q1, Q2, Q3, W2h, W2l);
  k_lif1<<<BLD_ / 4 / 256, 256, 0, stream>>>(x, s1);
  // pass 1: exact BN1 stats
  k_gemm1<1><<<dim3(H_ / 64, M1_ / 128), 256, 0, stream>>>(
      s1, Q0, Q1, Q2, Q3, bn1s, bn1q, nullptr, nullptr, nullptr, nullptr, nullptr);
  k_bnfinal<<<H_ / 256, 256, 0, stream>>>(bn1s, bn1q, mean1, rstd1, H_, 1.0 / (double)M1_);
  // pass 2: recompute exact + fp64 BN1-apply + fp64 LIF2 + transposed spikes
  k_gemm1<2><<<dim3(H_ / 64, (B_ * L_) / 32), 256, 0, stream>>>(
      s1, Q0, Q1, Q2, Q3, nullptr, nullptr, mean1, rstd1, gamma1, beta1, s2);
  // GEMM2 (bf16 split) + BN2 stats
  k_gemm2<<<dim3(D_ / 128, M1_ / 128), 256, 0, stream>>>(s2, W2h, W2l, O2, bn2s, bn2q);
  k_bnfinal<<<(D_ + 255) / 256, 256, 0, stream>>>(bn2s, bn2q, mean2, rstd2, D_, 1.0 / (double)M1_);
  k_bn2apply<<<dim3(D_ / 64, T_ * B_), 256, 0, stream>>>(O2, mean2, rstd2, gamma2, beta2, out);
}

// Round 4
// 499.928 us; speedup vs baseline: 1.3962x; 1.3962x over previous
//
#include <hip/hip_runtime.h>
#include <stdint.h>
#include <stddef.h>

#define T_ 4
#define B_ 64
#define L_ 64
#define D_ 768
#define H_ 3072
#define M1_ 16384      // T*B*L rows
#define BLD_ 3145728   // B*L*D
#define NW_ 2359296    // 3072*768
#define HL_ 196608     // H_*L_

using f4    = __attribute__((ext_vector_type(4))) float;
using int4v = __attribute__((ext_vector_type(4))) int;
using uc4   = __attribute__((ext_vector_type(4))) unsigned char;

static __device__ __forceinline__ void gload_lds16(const void* g, void* l) {
  __builtin_amdgcn_global_load_lds((const __attribute__((address_space(1))) void*)g,
                                   (__attribute__((address_space(3))) void*)l, 16, 0, 0);
}

// ---- weight conversion: W1 -> 4 i8 planes of round(w*2^33); W2 -> 2 i8 planes of round(w*2^17) ----
__global__ __launch_bounds__(256) void k_convert(
    const float* __restrict__ W1, const float* __restrict__ W2,
    signed char* __restrict__ Q0, signed char* __restrict__ Q1,
    signed char* __restrict__ Q2, signed char* __restrict__ Q3,
    signed char* __restrict__ R0, signed char* __restrict__ R1) {
  int i = blockIdx.x * 256 + threadIdx.x;
  if (i >= NW_) return;
  {
    double w = (double)W1[i];
    long long q = llrint(w * 8589934592.0);               // w * 2^33
    if (q >  2147483647LL) q =  2147483647LL;
    if (q < -2147483647LL) q = -2147483647LL;
    int ii = (int)q;
    int b0 = ((ii + 128) & 255) - 128; ii = (ii - b0) / 256;
    int b1 = ((ii + 128) & 255) - 128; ii = (ii - b1) / 256;
    int b2 = ((ii + 128) & 255) - 128; ii = (ii - b2) / 256;
    Q0[i] = (signed char)b0; Q1[i] = (signed char)b1;
    Q2[i] = (signed char)b2; Q3[i] = (signed char)ii;
  }
  {
    double w = (double)W2[i];
    long long q = llrint(w * 131072.0);                   // w * 2^17
    if (q >  32767LL) q =  32767LL;
    if (q < -32767LL) q = -32767LL;
    int ii = (int)q;
    int b0 = ((ii + 128) & 255) - 128;
    R0[i] = (signed char)b0;
    R1[i] = (signed char)((ii - b0) / 256);
  }
}

// ---- LIF1 in fp64, spikes as i8 {0,1} ----
__global__ __launch_bounds__(256) void k_lif1(const float* __restrict__ x,
                                              unsigned char* __restrict__ s1) {
  size_t i = ((size_t)blockIdx.x * 256 + threadIdx.x) * 4;
  double v0 = 0., v1 = 0., v2 = 0., v3 = 0.;
  #pragma unroll
  for (int t = 0; t < T_; ++t) {
    f4 xt = *(const f4*)(x + (size_t)t * BLD_ + i);
    v0 = v0 + ((double)xt.x - v0) * 0.5;
    v1 = v1 + ((double)xt.y - v1) * 0.5;
    v2 = v2 + ((double)xt.z - v2) * 0.5;
    v3 = v3 + ((double)xt.w - v3) * 0.5;
    uc4 s;
    s.x = (v0 >= 1.0) ? 1 : 0;
    s.y = (v1 >= 1.0) ? 1 : 0;
    s.z = (v2 >= 1.0) ? 1 : 0;
    s.w = (v3 >= 1.0) ? 1 : 0;
    *(uc4*)(s1 + (size_t)t * BLD_ + i) = s;
    v0 = s.x ? 0. : v0;
    v1 = s.y ? 0. : v1;
    v2 = s.z ? 0. : v2;
    v3 = s.w ? 0. : v3;
  }
}

// ---- exact integer GEMM1 (4 i8 planes, scale 2^33), dbuf 2-phase + swizzled LDS ----
// tile 128m x 64n, BK=64, 4 waves (2x2 over 64m x 32n).
// MODE 1: fp64 partial column stats (grid.y = contiguous 128-row m-tiles)
// MODE 2: BN1-apply(fp64) + fp64 LIF2 + transposed i8 spike write
//         (grid.y = bl-chunks: rows m = t*4096 + by*32 + j)
template <int MODE>
__global__ __launch_bounds__(256) void k_gemm1(
    const unsigned char* __restrict__ A,
    const signed char* __restrict__ Q0, const signed char* __restrict__ Q1,
    const signed char* __restrict__ Q2, const signed char* __restrict__ Q3,
    double* __restrict__ partS, double* __restrict__ partQ,
    const double* __restrict__ mean, const double* __restrict__ rstd,
    const float* __restrict__ gamma, const float* __restrict__ beta,
    signed char* __restrict__ s2) {
  constexpr int SMEM_BYTES = (MODE == 2) ? 65536 : 49152;
  __shared__ __align__(16) char smem[SMEM_BYTES];   // 2 bufs x (A 8KB + B 16KB); MODE2 overlays 64KB fp64 tile

  const int tid  = threadIdx.x;
  const int lane = tid & 63;
  const int w    = tid >> 6;
  const int wr = tid >> 7;
  const int wc = (tid >> 6) & 1;
  const int n0 = blockIdx.x * 64;
  const int by = blockIdx.y;

  auto grow = [&](int r) -> size_t {
    if (MODE == 2) return (size_t)4096 * (r >> 5) + (size_t)by * 32 + (r & 31);
    return (size_t)by * 128 + r;
  };

  // staging slots (physical) with inverse-swizzled global sources
  const int aIdx0 = w * 128 + lane;
  const int aIdx1 = aIdx0 + 64;
  const int ar0 = aIdx0 >> 2, ar1 = aIdx1 >> 2;
  const int ac0 = (aIdx0 & 3) ^ ((ar0 >> 1) & 3);
  const int ac1 = (aIdx1 & 3) ^ ((ar1 >> 1) & 3);
  const unsigned char* Ag0 = A + grow(ar0) * 768 + ac0 * 16;
  const unsigned char* Ag1 = A + grow(ar1) * 768 + ac1 * 16;
  const int bIdx = w * 64 + lane;
  const int brS = bIdx >> 2;
  const int bcS = (bIdx & 3) ^ ((brS >> 1) & 3);
  const signed char* Bg[4];
  Bg[0] = Q0 + (size_t)(n0 + brS) * 768 + bcS * 16;
  Bg[1] = Q1 + (size_t)(n0 + brS) * 768 + bcS * 16;
  Bg[2] = Q2 + (size_t)(n0 + brS) * 768 + bcS * 16;
  Bg[3] = Q3 + (size_t)(n0 + brS) * 768 + bcS * 16;

  int4v acc[4][4][2] = {};   // [plane][m][n]
  const int arow = wr * 64 + (lane & 15);
  const int clog = lane >> 4;

  // prologue: stage k0=0 into buf0
  gload_lds16(Ag0, smem + aIdx0 * 16);
  gload_lds16(Ag1, smem + aIdx1 * 16);
  #pragma unroll
  for (int p = 0; p < 4; ++p)
    gload_lds16(Bg[p], smem + 8192 + p * 4096 + bIdx * 16);
  __syncthreads();

  for (int t = 0; t < 12; ++t) {
    const int cur = t & 1;
    if (t < 11) {                       // issue next tile BEFORE compute (T3-minimum)
      const int kn = (t + 1) * 64;
      char* dst = smem + (cur ^ 1) * 24576;
      gload_lds16(Ag0 + kn, dst + aIdx0 * 16);
      gload_lds16(Ag1 + kn, dst + aIdx1 * 16);
      #pragma unroll
      for (int p = 0; p < 4; ++p)
        gload_lds16(Bg[p] + kn, dst + 8192 + p * 4096 + bIdx * 16);
    }
    const signed char* ldsA = (const signed char*)smem + cur * 24576;
    const signed char* ldsB = ldsA + 8192;
    int4v av[4], bv[2][4];
    #pragma unroll
    for (int m = 0; m < 4; ++m) {
      const int r = arow + m * 16;
      const int cp = clog ^ ((r >> 1) & 3);
      av[m] = *(const int4v*)(ldsA + r * 64 + cp * 16);
    }
    #pragma unroll
    for (int n = 0; n < 2; ++n) {
      const int r = wc * 32 + n * 16 + (lane & 15);
      const int cp = clog ^ ((r >> 1) & 3);
      #pragma unroll
      for (int p = 0; p < 4; ++p)
        bv[n][p] = *(const int4v*)(ldsB + p * 4096 + r * 64 + cp * 16);
    }
    #pragma unroll
    for (int p = 0; p < 4; ++p)
      #pragma unroll
      for (int m = 0; m < 4; ++m)
        #pragma unroll
        for (int n = 0; n < 2; ++n)
          acc[p][m][n] = __builtin_amdgcn_mfma_i32_16x16x64_i8(av[m], bv[n][p], acc[p][m][n], 0, 0, 0);
    __syncthreads();                    // single drain per tile
  }

  auto H64 = [&](int m, int n, int r) -> double {
    long long v = ((long long)acc[3][m][n][r] << 24) + ((long long)acc[2][m][n][r] << 16)
                + ((long long)acc[1][m][n][r] << 8) + (long long)acc[0][m][n][r];
    return (double)v * (1.0 / 8589934592.0);
  };

  if constexpr (MODE == 1) {
    #pragma unroll
    for (int n = 0; n < 2; ++n) {
      double s = 0.0, q = 0.0;
      #pragma unroll
      for (int m = 0; m < 4; ++m)
        #pragma unroll
        for (int r = 0; r < 4; ++r) {
          double v = H64(m, n, r);
          s += v;
          q += v * v;
        }
      s += __shfl_xor(s, 16);
      q += __shfl_xor(q, 16);
      s += __shfl_xor(s, 32);
      q += __shfl_xor(q, 32);
      if ((lane >> 4) == 0) {
        int col = n0 + wc * 32 + n * 16 + lane;
        partS[(size_t)(by * 2 + wr) * H_ + col] = s;   // contention-free partials
        partQ[(size_t)(by * 2 + wr) * H_ + col] = q;
      }
    }
  }

  if constexpr (MODE == 2) {
    double* smE = (double*)smem;   // [128][64] fp64 g-values (overlays both bufs)
    double mn[2], rs[2], gm[2], bt[2];
    #pragma unroll
    for (int n = 0; n < 2; ++n) {
      int c = n0 + wc * 32 + n * 16 + (lane & 15);
      mn[n] = mean[c]; rs[n] = rstd[c];
      gm[n] = (double)gamma[c]; bt[n] = (double)beta[c];
    }
    #pragma unroll
    for (int m = 0; m < 4; ++m)
      #pragma unroll
      for (int n = 0; n < 2; ++n)
        #pragma unroll
        for (int r = 0; r < 4; ++r) {
          int row = wr * 64 + m * 16 + ((lane >> 4) << 2) + r;
          int col = wc * 32 + n * 16 + (lane & 15);
          smE[row * 64 + col] = (H64(m, n, r) - mn[n]) * rs[n] * gm[n] + bt[n];
        }
    __syncthreads();
    // fp64 LIF chains over t; spikes (i8 {0,1}) in the reference's (T*B, H, L) layout
    const int bI = by >> 1;
    const int l0 = (by & 1) * 32;
    const int j0 = (tid & 7) * 4;
    #pragma unroll
    for (int it = 0; it < 2; ++it) {
      const int hl = (tid >> 3) + it * 32;
      const size_t hg = (size_t)(n0 + hl);
      unsigned int pack[4];   // 4 spike bytes per t
      #pragma unroll
      for (int t = 0; t < 4; ++t) pack[t] = 0;
      #pragma unroll
      for (int jj = 0; jj < 4; ++jj) {
        double v = 0.;
        #pragma unroll
        for (int t = 0; t < 4; ++t) {
          double g = smE[(t * 32 + j0 + jj) * 64 + hl];
          v = v + (g - v) * 0.5;
          bool s = (v >= 1.0);
          if (s) pack[t] |= (1u << (jj * 8));
          v = s ? 0. : v;
        }
      }
      #pragma unroll
      for (int t = 0; t < 4; ++t)
        *(unsigned int*)(s2 + (size_t)(t * 64 + bI) * HL_ + hg * 64 + l0 + j0) = pack[t];
    }
  }
}

// ---- GEMM2: exact integer (2 i8 planes, scale 2^17), dbuf 2-phase + swizzle ----
// tile 128m x 128n, BK=64, 4 waves (2x2 over 64x64). C fp32 + fp64 partial stats.
__global__ __launch_bounds__(256) void k_gemm2(
    const signed char* __restrict__ A,
    const signed char* __restrict__ R0, const signed char* __restrict__ R1,
    float* __restrict__ C,
    double* __restrict__ partS, double* __restrict__ partQ) {
  __shared__ __align__(16) char smem[49152];   // 2 bufs x (A 8KB + P0 8KB + P1 8KB)
  const int tid  = threadIdx.x;
  const int lane = tid & 63;
  const int w    = tid >> 6;
  const int wr = tid >> 7;
  const int wc = (tid >> 6) & 1;
  const int n0 = blockIdx.x * 128;
  const int by = blockIdx.y;

  const int i0 = w * 128 + lane;
  const int i1 = i0 + 64;
  const int r0s = i0 >> 2, r1s = i1 >> 2;
  const int c0s = (i0 & 3) ^ ((r0s >> 1) & 3);
  const int c1s = (i1 & 3) ^ ((r1s >> 1) & 3);
  const signed char* Ag0 = A + (size_t)(by * 128 + r0s) * 3072 + c0s * 16;
  const signed char* Ag1 = A + (size_t)(by * 128 + r1s) * 3072 + c1s * 16;
  const signed char* P0g0 = R0 + (size_t)(n0 + r0s) * 3072 + c0s * 16;
  const signed char* P0g1 = R0 + (size_t)(n0 + r1s) * 3072 + c1s * 16;
  const signed char* P1g0 = R1 + (size_t)(n0 + r0s) * 3072 + c0s * 16;
  const signed char* P1g1 = R1 + (size_t)(n0 + r1s) * 3072 + c1s * 16;

  int4v acc[2][4][4] = {};   // [plane][m][n]
  const int arow = wr * 64 + (lane & 15);
  const int brow = wc * 64 + (lane & 15);
  const int clog = lane >> 4;

  gload_lds16(Ag0, smem + i0 * 16);
  gload_lds16(Ag1, smem + i1 * 16);
  gload_lds16(P0g0, smem + 8192 + i0 * 16);
  gload_lds16(P0g1, smem + 8192 + i1 * 16);
  gload_lds16(P1g0, smem + 16384 + i0 * 16);
  gload_lds16(P1g1, smem + 16384 + i1 * 16);
  __syncthreads();

  for (int t = 0; t < 48; ++t) {
    const int cur = t & 1;
    if (t < 47) {
      const int kn = (t + 1) * 64;
      char* dst = smem + (cur ^ 1) * 24576;
      gload_lds16(Ag0 + kn, dst + i0 * 16);
      gload_lds16(Ag1 + kn, dst + i1 * 16);
      gload_lds16(P0g0 + kn, dst + 8192 + i0 * 16);
      gload_lds16(P0g1 + kn, dst + 8192 + i1 * 16);
      gload_lds16(P1g0 + kn, dst + 16384 + i0 * 16);
      gload_lds16(P1g1 + kn, dst + 16384 + i1 * 16);
    }
    const signed char* ldsA = (const signed char*)smem + cur * 24576;
    int4v av[4], bv[2][4];
    #pragma unroll
    for (int m = 0; m < 4; ++m) {
      const int r = arow + m * 16;
      const int cp = clog ^ ((r >> 1) & 3);
      av[m] = *(const int4v*)(ldsA + r * 64 + cp * 16);
    }
    #pragma unroll
    for (int n = 0; n < 4; ++n) {
      const int r = brow + n * 16;
      const int cp = clog ^ ((r >> 1) & 3);
      bv[0][n] = *(const int4v*)(ldsA + 8192 + r * 64 + cp * 16);
      bv[1][n] = *(const int4v*)(ldsA + 16384 + r * 64 + cp * 16);
    }
    #pragma unroll
    for (int p = 0; p < 2; ++p)
      #pragma unroll
      for (int m = 0; m < 4; ++m)
        #pragma unroll
        for (int n = 0; n < 4; ++n)
          acc[p][m][n] = __builtin_amdgcn_mfma_i32_16x16x64_i8(av[m], bv[p][n], acc[p][m][n], 0, 0, 0);
    __syncthreads();
  }

  const int r0o = by * 128 + wr * 64 + ((lane >> 4) << 2);
  const int c0o = n0 + wc * 64 + (lane & 15);
  #pragma unroll
  for (int n = 0; n < 4; ++n) {
    double s = 0.0, q = 0.0;
    #pragma unroll
    for (int m = 0; m < 4; ++m)
      #pragma unroll
      for (int r = 0; r < 4; ++r) {
        int hv = acc[0][m][n][r] + 256 * acc[1][m][n][r];
        double h = (double)hv * (1.0 / 131072.0);
        C[(size_t)(r0o + m * 16 + r) * 768 + (c0o + n * 16)] = (float)h;
        s += h;
        q += h * h;
      }
    s += __shfl_xor(s, 16);
    q += __shfl_xor(q, 16);
    s += __shfl_xor(s, 32);
    q += __shfl_xor(q, 32);
    if ((lane >> 4) == 0) {
      int col = n0 + wc * 64 + n * 16 + lane;
      partS[(size_t)(by * 2 + wr) * D_ + col] = s;
      partQ[(size_t)(by * 2 + wr) * D_ + col] = q;
    }
  }
}

// ---- reduce 256 partials -> mean, rstd (fp64) ----
__global__ __launch_bounds__(256) void k_bnred(
    const double* __restrict__ pS, const double* __restrict__ pQ,
    double* __restrict__ mean, double* __restrict__ rstd, int N, double invM) {
  int i = blockIdx.x * 256 + threadIdx.x;
  if (i >= N) return;
  double s = 0.0, q = 0.0;
  for (int p = 0; p < 256; ++p) {
    s += pS[(size_t)p * N + i];
    q += pQ[(size_t)p * N + i];
  }
  double m = s * invM;
  double v = q * invM - m * m;
  mean[i] = m;
  rstd[i] = 1.0 / sqrt(v + 1e-5);
}

// ---- BN2-apply (fp64) + (L,D)->(D,L) per-tb transpose -> fp32 out ----
__global__ __launch_bounds__(256) void k_bn2apply(
    const float* __restrict__ O, const double* __restrict__ mean,
    const double* __restrict__ rstd, const float* __restrict__ gamma,
    const float* __restrict__ beta, float* __restrict__ out) {
  __shared__ __align__(16) float sm[64 * 65];
  const int tid = threadIdx.x;
  const int d0 = blockIdx.x * 64;
  const int tb = blockIdx.y;
  const int doff = tid & 63;
  const int lgrp = tid >> 6;
  const double mn = mean[d0 + doff];
  const double rs = rstd[d0 + doff];
  const double gm = (double)gamma[d0 + doff];
  const double bt = (double)beta[d0 + doff];
  #pragma unroll 4
  for (int p = 0; p < 16; ++p) {
    const int l = p * 4 + lgrp;
    double v = (double)O[((size_t)tb * 64 + l) * D_ + d0 + doff];
    sm[doff * 65 + l] = (float)(((v - mn) * rs) * gm + bt);
  }
  __syncthreads();
  const int l4 = (tid & 15) * 4;
  const int db = tid >> 4;
  #pragma unroll
  for (int p = 0; p < 4; ++p) {
    const int dd = p * 16 + db;
    f4 wv;
    wv.x = sm[dd * 65 + l4 + 0];
    wv.y = sm[dd * 65 + l4 + 1];
    wv.z = sm[dd * 65 + l4 + 2];
    wv.w = sm[dd * 65 + l4 + 3];
    *(f4*)(out + (size_t)tb * (D_ * L_) + (size_t)(d0 + dd) * 64 + l4) = wv;
  }
}

extern "C" void kernel_launch(void* const* d_in, const int* in_sizes, int n_in,
                              void* d_out, int out_size, void* d_ws, size_t ws_size,
                              hipStream_t stream) {
  const float* x      = (const float*)d_in[0];
  const float* W1     = (const float*)d_in[1];
  const float* gamma1 = (const float*)d_in[2];
  const float* beta1  = (const float*)d_in[3];
  const float* W2     = (const float*)d_in[4];
  const float* gamma2 = (const float*)d_in[5];
  const float* beta2  = (const float*)d_in[6];
  float* out = (float*)d_out;
  (void)in_sizes; (void)n_in; (void)out_size; (void)ws_size;

  // s1 (i8 spikes, 12.6 MB) lives in d_out; d_out is fully rewritten at the end.
  unsigned char* s1 = (unsigned char*)d_out;

  char* ws = (char*)d_ws;
  size_t off = 0;
  auto alloc = [&](size_t bytes) -> void* {
    void* p = ws + off;
    off += (bytes + 255) & ~(size_t)255;
    return p;
  };
  signed char* Q0 = (signed char*)alloc(NW_);
  signed char* Q1 = (signed char*)alloc(NW_);
  signed char* Q2 = (signed char*)alloc(NW_);
  signed char* Q3 = (signed char*)alloc(NW_);
  signed char* R0 = (signed char*)alloc(NW_);
  signed char* R1 = (signed char*)alloc(NW_);
  signed char* s2 = (signed char*)alloc((size_t)M1_ * H_);            // 50.3 MB
  float* O2       = (float*)alloc((size_t)M1_ * D_ * 4);              // 50.3 MB
  double* pS1 = (double*)alloc((size_t)256 * H_ * 8);                 // 6.3 MB
  double* pQ1 = (double*)alloc((size_t)256 * H_ * 8);
  double* pS2 = (double*)alloc((size_t)256 * D_ * 8);                 // 1.6 MB
  double* pQ2 = (double*)alloc((size_t)256 * D_ * 8);
  double* mean1 = (double*)alloc((size_t)H_ * 8);
  double* rstd1 = (double*)alloc((size_t)H_ * 8);
  double* mean2 = (double*)alloc((size_t)D_ * 8);
  double* rstd2 = (double*)alloc((size_t)D_ * 8);

  k_convert<<<NW_ / 256, 256, 0, stream>>>(W1, W2, Q0, Q1, Q2, Q3, R0, R1);
  k_lif1<<<BLD_ / 4 / 256, 256, 0, stream>>>(x, s1);
  // pass 1: exact BN1 partial stats
  k_gemm1<1><<<dim3(H_ / 64, M1_ / 128), 256, 0, stream>>>(
      s1, Q0, Q1, Q2, Q3, pS1, pQ1, nullptr, nullptr, nullptr, nullptr, nullptr);
  k_bnred<<<H_ / 256, 256, 0, stream>>>(pS1, pQ1, mean1, rstd1, H_, 1.0 / (double)M1_);
  // pass 2: recompute exact + fp64 BN1-apply + fp64 LIF2 + transposed i8 spikes
  k_gemm1<2><<<dim3(H_ / 64, (B_ * L_) / 32), 256, 0, stream>>>(
      s1, Q0, Q1, Q2, Q3, nullptr, nullptr, mean1, rstd1, gamma1, beta1, s2);
  // GEMM2 (exact i8 x 2 planes) + BN2 partial stats
  k_gemm2<<<dim3(D_ / 128, M1_ / 128), 256, 0, stream>>>(s2, R0, R1, O2, pS2, pQ2);
  k_bnred<<<(D_ + 255) / 256, 256, 0, stream>>>(pS2, pQ2, mean2, rstd2, D_, 1.0 / (double)M1_);
  k_bn2apply<<<dim3(D_ / 64, T_ * B_), 256, 0, stream>>>(O2, mean2, rstd2, gamma2, beta2, out);
}

// Round 7
// 473.287 us; speedup vs baseline: 1.4748x; 1.0563x over previous
//
#include <hip/hip_runtime.h>
#include <stdint.h>
#include <stddef.h>

#define T_ 4
#define B_ 64
#define L_ 64
#define D_ 768
#define H_ 3072
#define M1_ 16384      // T*B*L rows
#define BLD_ 3145728   // B*L*D
#define NW_ 2359296    // 3072*768
#define HL_ 196608     // H_*L_

using f4    = __attribute__((ext_vector_type(4))) float;
using int4v = __attribute__((ext_vector_type(4))) int;
using uc4   = __attribute__((ext_vector_type(4))) unsigned char;
using uc16  = __attribute__((ext_vector_type(16))) unsigned char;
using ui2   = __attribute__((ext_vector_type(2))) unsigned int;

static __device__ __forceinline__ void gload_lds16(const void* g, void* l) {
  __builtin_amdgcn_global_load_lds((const __attribute__((address_space(1))) void*)g,
                                   (__attribute__((address_space(3))) void*)l, 16, 0, 0);
}

#define INV33 (1.0/8589934592.0)

// ---- weights: W1 -> int32 q (scale 2^33, clamp 126*2^24) + 4 i8 digit planes;
// ----          W2 -> 2 i8 digit planes (scale 2^17, clamp 127*256)
__global__ __launch_bounds__(256) void k_convert(
    const float* __restrict__ W1, const float* __restrict__ W2,
    signed char* __restrict__ Q0, signed char* __restrict__ Q1,
    signed char* __restrict__ Q2, signed char* __restrict__ Q3,
    int* __restrict__ Qint,
    signed char* __restrict__ R0, signed char* __restrict__ R1) {
  int i = blockIdx.x * 256 + threadIdx.x;
  if (i >= NW_) return;
  {
    double w = (double)W1[i];
    long long q = llrint(w * 8589934592.0);
    if (q >  2113929216LL) q =  2113929216LL;
    if (q < -2113929216LL) q = -2113929216LL;
    int ii = (int)q;
    Qint[i] = ii;
    int b0 = ((ii + 128) & 255) - 128; ii = (ii - b0) >> 8;
    int b1 = ((ii + 128) & 255) - 128; ii = (ii - b1) >> 8;
    int b2 = ((ii + 128) & 255) - 128; ii = (ii - b2) >> 8;
    Q0[i] = (signed char)b0; Q1[i] = (signed char)b1;
    Q2[i] = (signed char)b2; Q3[i] = (signed char)ii;
  }
  {
    double w = (double)W2[i];
    long long q = llrint(w * 131072.0);
    if (q >  32512LL) q =  32512LL;
    if (q < -32512LL) q = -32512LL;
    int ii = (int)q;
    int b0 = ((ii + 128) & 255) - 128;
    R0[i] = (signed char)b0;
    R1[i] = (signed char)((ii - b0) >> 8);
  }
}

// ---- LIF1 in fp64, spikes as i8 {0,1} ----
__global__ __launch_bounds__(256) void k_lif1(const float* __restrict__ x,
                                              unsigned char* __restrict__ s1) {
  size_t i = ((size_t)blockIdx.x * 256 + threadIdx.x) * 4;
  double v0 = 0., v1 = 0., v2 = 0., v3 = 0.;
  #pragma unroll
  for (int t = 0; t < T_; ++t) {
    f4 xt = *(const f4*)(x + (size_t)t * BLD_ + i);
    v0 = v0 + ((double)xt.x - v0) * 0.5;
    v1 = v1 + ((double)xt.y - v1) * 0.5;
    v2 = v2 + ((double)xt.z - v2) * 0.5;
    v3 = v3 + ((double)xt.w - v3) * 0.5;
    uc4 s;
    s.x = (v0 >= 1.0) ? 1 : 0;
    s.y = (v1 >= 1.0) ? 1 : 0;
    s.z = (v2 >= 1.0) ? 1 : 0;
    s.w = (v3 >= 1.0) ? 1 : 0;
    *(uc4*)(s1 + (size_t)t * BLD_ + i) = s;
    v0 = s.x ? 0. : v0;
    v1 = s.y ? 0. : v1;
    v2 = s.z ? 0. : v2;
    v3 = s.w ? 0. : v3;
  }
}

// ---- transpose s1 (16384 x 768) -> s1T (768 x 16384), + column spike counts ----
// grid (12 dblk, 64 blblk, 4 t); s1T[d][t*4096 + bl]
__global__ __launch_bounds__(256) void k_s1t(const unsigned char* __restrict__ s1,
                                             unsigned char* __restrict__ sT,
                                             int* __restrict__ colsum) {
  __shared__ __align__(16) unsigned char sm[64 * 80];
  const int tid = threadIdx.x;
  const int d0 = blockIdx.x * 64;
  const int bl0 = blockIdx.y * 64;
  const int t = blockIdx.z;
  {
    const int i = tid >> 2, ch = tid & 3;
    uc16 v = *(const uc16*)(s1 + (size_t)t * BLD_ + (size_t)(bl0 + i) * 768 + d0 + ch * 16);
    *(uc16*)(sm + i * 80 + ch * 16) = v;
  }
  __syncthreads();
  {
    const int d = tid >> 2, oc = tid & 3;
    union { uc16 v; unsigned char b[16]; } u;
    int s = 0;
    #pragma unroll
    for (int jj = 0; jj < 16; ++jj) {
      unsigned char c = sm[(oc * 16 + jj) * 80 + d];
      u.b[jj] = c;
      s += c;
    }
    *(uc16*)(sT + (size_t)(d0 + d) * M1_ + t * 4096 + bl0 + oc * 16) = u.v;
    s += __shfl_xor(s, 1);
    s += __shfl_xor(s, 2);
    if ((tid & 3) == 0) atomicAdd(&colsum[d0 + d], s);
  }
}

// ---- Gram: G = S^T S (768x768 int), splitK partials. grid (36 tilepair, 8 ks) ----
// Safe dbuf: stage-next issued BEFORE compute, one __syncthreads per iter (r4 structure).
__global__ __launch_bounds__(256) void k_gram(const unsigned char* __restrict__ sT,
                                              int* __restrict__ Gpart) {
  __shared__ __align__(16) char smem[32768];   // 2 x (A 8KB + B 8KB)
  const int tid = threadIdx.x;
  const int lane = tid & 63;
  const int wr = tid >> 7;
  const int wc = (tid >> 6) & 1;
  const int tr = blockIdx.x / 6, tc = blockIdx.x % 6;
  const int ks = blockIdx.y;
  const size_t m0 = (size_t)ks * 2048;

  const int s0 = tid, s1i = tid + 256;
  const int rA0 = s0 >> 2, rA1 = s1i >> 2;
  const int cA0 = (s0 & 3) ^ ((rA0 >> 1) & 3);
  const int cA1 = (s1i & 3) ^ ((rA1 >> 1) & 3);
  const unsigned char* Ag0 = sT + (size_t)(tr * 128 + rA0) * M1_ + m0 + cA0 * 16;
  const unsigned char* Ag1 = sT + (size_t)(tr * 128 + rA1) * M1_ + m0 + cA1 * 16;
  const unsigned char* Bg0 = sT + (size_t)(tc * 128 + rA0) * M1_ + m0 + cA0 * 16;
  const unsigned char* Bg1 = sT + (size_t)(tc * 128 + rA1) * M1_ + m0 + cA1 * 16;

  int4v acc[4][4] = {};
  const int clog = lane >> 4;

  gload_lds16(Ag0, smem + s0 * 16);
  gload_lds16(Ag1, smem + s1i * 16);
  gload_lds16(Bg0, smem + 8192 + s0 * 16);
  gload_lds16(Bg1, smem + 8192 + s1i * 16);
  __syncthreads();

  for (int kt = 0; kt < 32; ++kt) {
    if (kt < 31) {
      const int kn = (kt + 1) * 64;
      char* dst = smem + ((kt + 1) & 1) * 16384;
      gload_lds16(Ag0 + kn, dst + s0 * 16);
      gload_lds16(Ag1 + kn, dst + s1i * 16);
      gload_lds16(Bg0 + kn, dst + 8192 + s0 * 16);
      gload_lds16(Bg1 + kn, dst + 8192 + s1i * 16);
    }
    const signed char* ldsA = (const signed char*)smem + (kt & 1) * 16384;
    const signed char* ldsB = ldsA + 8192;
    int4v av[4], bv[4];
    #pragma unroll
    for (int m = 0; m < 4; ++m) {
      const int r = wr * 64 + m * 16 + (lane & 15);
      const int cp = clog ^ ((r >> 1) & 3);
      av[m] = *(const int4v*)(ldsA + r * 64 + cp * 16);
    }
    #pragma unroll
    for (int n = 0; n < 4; ++n) {
      const int r = wc * 64 + n * 16 + (lane & 15);
      const int cp = clog ^ ((r >> 1) & 3);
      bv[n] = *(const int4v*)(ldsB + r * 64 + cp * 16);
    }
    #pragma unroll
    for (int m = 0; m < 4; ++m)
      #pragma unroll
      for (int n = 0; n < 4; ++n)
        acc[m][n] = __builtin_amdgcn_mfma_i32_16x16x64_i8(av[m], bv[n], acc[m][n], 0, 0, 0);
    __syncthreads();   // drains vmcnt+lgkmcnt: staged tile landed, all reads done
  }

  const int r0 = tr * 128 + wr * 64 + (clog << 2);
  const int c0 = tc * 128 + wc * 64 + (lane & 15);
  #pragma unroll
  for (int m = 0; m < 4; ++m)
    #pragma unroll
    for (int n = 0; n < 4; ++n)
      #pragma unroll
      for (int rr = 0; rr < 4; ++rr)
        Gpart[((size_t)ks * 768 + r0 + m * 16 + rr) * 768 + c0 + n * 16] = acc[m][n][rr];
}

// ---- reduce 8 Gram partials -> 2 i8 digit planes (G = g0 + 256*g1, G<=16384) ----
__global__ __launch_bounds__(256) void k_gramred(const int* __restrict__ Gpart,
                                                 signed char* __restrict__ g0,
                                                 signed char* __restrict__ g1) {
  int i = blockIdx.x * 256 + threadIdx.x;
  if (i >= 768 * 768) return;
  int G = 0;
  #pragma unroll
  for (int ks = 0; ks < 8; ++ks) G += Gpart[(size_t)ks * 768 * 768 + i];
  int b0 = ((G + 128) & 255) - 128;
  g0[i] = (signed char)b0;
  g1[i] = (signed char)((G - b0) >> 8);
}

// ---- Y = G * Q  (exact via 2x4 i8 plane pairs, fp64 fold), YT[c][k] ----
// tile 64k x 64c, 4 waves (wave w -> k rows w*16..+15). grid (12, 48)
__global__ __launch_bounds__(256) void k_gq(
    const signed char* __restrict__ g0, const signed char* __restrict__ g1,
    const signed char* __restrict__ Q0, const signed char* __restrict__ Q1,
    const signed char* __restrict__ Q2, const signed char* __restrict__ Q3,
    double* __restrict__ YT) {
  __shared__ __align__(16) char smem[49152];   // 2 x (A0 4K | A1 4K | B0..B3 16K)
  const int tid = threadIdx.x;
  const int lane = tid & 63;
  const int w = tid >> 6;
  const int k0 = blockIdx.x * 64;
  const int c0 = blockIdx.y * 64;

  const int row = tid >> 2;
  const int ch = (tid & 3) ^ ((row >> 1) & 3);
  const signed char* Ag[2] = { g0 + (size_t)(k0 + row) * 768 + ch * 16,
                               g1 + (size_t)(k0 + row) * 768 + ch * 16 };
  const signed char* Bg[4] = { Q0 + (size_t)(c0 + row) * 768 + ch * 16,
                               Q1 + (size_t)(c0 + row) * 768 + ch * 16,
                               Q2 + (size_t)(c0 + row) * 768 + ch * 16,
                               Q3 + (size_t)(c0 + row) * 768 + ch * 16 };

  int4v acc[8][4] = {};   // [a*4+p][n]
  const int clog = lane >> 4;

  #pragma unroll
  for (int a = 0; a < 2; ++a) gload_lds16(Ag[a], smem + a * 4096 + tid * 16);
  #pragma unroll
  for (int p = 0; p < 4; ++p) gload_lds16(Bg[p], smem + 8192 + p * 4096 + tid * 16);
  __syncthreads();

  for (int kt = 0; kt < 12; ++kt) {
    if (kt < 11) {
      const int kn = (kt + 1) * 64;
      char* dst = smem + ((kt + 1) & 1) * 24576;
      #pragma unroll
      for (int a = 0; a < 2; ++a) gload_lds16(Ag[a] + kn, dst + a * 4096 + tid * 16);
      #pragma unroll
      for (int p = 0; p < 4; ++p) gload_lds16(Bg[p] + kn, dst + 8192 + p * 4096 + tid * 16);
    }
    const signed char* base = (const signed char*)smem + (kt & 1) * 24576;
    const int ar = w * 16 + (lane & 15);
    const int acp = clog ^ ((ar >> 1) & 3);
    int4v av[2];
    #pragma unroll
    for (int a = 0; a < 2; ++a)
      av[a] = *(const int4v*)(base + a * 4096 + ar * 64 + acp * 16);
    #pragma unroll
    for (int p = 0; p < 4; ++p) {
      int4v bv[4];
      #pragma unroll
      for (int n = 0; n < 4; ++n) {
        const int br = n * 16 + (lane & 15);
        const int bcp = clog ^ ((br >> 1) & 3);
        bv[n] = *(const int4v*)(base + 8192 + p * 4096 + br * 64 + bcp * 16);
      }
      #pragma unroll
      for (int a = 0; a < 2; ++a)
        #pragma unroll
        for (int n = 0; n < 4; ++n)
          acc[a * 4 + p][n] = __builtin_amdgcn_mfma_i32_16x16x64_i8(av[a], bv[n], acc[a * 4 + p][n], 0, 0, 0);
    }
    __syncthreads();
  }

  #pragma unroll
  for (int n = 0; n < 4; ++n)
    #pragma unroll
    for (int r = 0; r < 4; ++r) {
      int A0 = acc[0][n][r] + (acc[4][n][r] << 8);
      int A1 = acc[1][n][r] + (acc[5][n][r] << 8);
      int A2 = acc[2][n][r] + (acc[6][n][r] << 8);
      int A3 = acc[3][n][r] + (acc[7][n][r] << 8);
      double Y = (double)A0 + 256.0 * (double)A1 + 65536.0 * (double)A2 + 16777216.0 * (double)A3;
      const int k = k0 + w * 16 + clog * 4 + r;
      const int c = c0 + n * 16 + (lane & 15);
      YT[(size_t)c * 768 + k] = Y;
    }
}

// ---- BN1 stats: mean_c = colsum.q_c/(M*2^33); E[h^2]_c = q_c.Y_c/(M*2^66) ----
__global__ __launch_bounds__(256) void k_stats1(
    const double* __restrict__ YT, const int* __restrict__ Qint,
    const int* __restrict__ colsum,
    double* __restrict__ mean, double* __restrict__ rstd) {
  __shared__ double red[8];
  const int c = blockIdx.x;
  const int tid = threadIdx.x;
  double s2 = 0.0, sm = 0.0;
  for (int k = tid; k < 768; k += 256) {
    double q = (double)Qint[(size_t)c * 768 + k];
    s2 += q * YT[(size_t)c * 768 + k];
    sm += q * (double)colsum[k];
  }
  #pragma unroll
  for (int o = 32; o; o >>= 1) { s2 += __shfl_xor(s2, o); sm += __shfl_xor(sm, o); }
  if ((tid & 63) == 0) { red[(tid >> 6) * 2] = s2; red[(tid >> 6) * 2 + 1] = sm; }
  __syncthreads();
  if (tid == 0) {
    double S2 = red[0] + red[2] + red[4] + red[6];
    double SM = red[1] + red[3] + red[5] + red[7];
    double mn = SM * INV33 * (1.0 / 16384.0);
    double Eh2 = S2 * INV33 * INV33 * (1.0 / 16384.0);
    double var = Eh2 - mn * mn;
    mean[c] = mn;
    rstd[c] = 1.0 / sqrt(var + 1e-5);
  }
}

// ---- GEMM1 + BN1-apply + fp64 LIF2 + transposed i8 spike write ----
// tile 128m x 64n (m rows: t*4096 + by*32 + j), safe dbuf, 48KB LDS -> 3 blk/CU
__global__ __launch_bounds__(256) void k_bnlif(
    const unsigned char* __restrict__ A,
    const signed char* __restrict__ Q0, const signed char* __restrict__ Q1,
    const signed char* __restrict__ Q2, const signed char* __restrict__ Q3,
    const double* __restrict__ mean, const double* __restrict__ rstd,
    const float* __restrict__ gamma, const float* __restrict__ beta,
    signed char* __restrict__ s2) {
  __shared__ __align__(16) char smem[49152];   // 2 x (A 8KB + B 16KB) ; epilogue lo32/hi16 overlay
  const int tid  = threadIdx.x;
  const int lane = tid & 63;
  const int w    = tid >> 6;
  const int wr = tid >> 7;
  const int wc = (tid >> 6) & 1;
  const int n0 = blockIdx.x * 64;
  const int by = blockIdx.y;

  auto grow = [&](int r) -> size_t {
    return (size_t)4096 * (r >> 5) + (size_t)by * 32 + (r & 31);
  };
  const int aIdx0 = w * 128 + lane;
  const int aIdx1 = aIdx0 + 64;
  const int ar0 = aIdx0 >> 2, ar1 = aIdx1 >> 2;
  const int ac0 = (aIdx0 & 3) ^ ((ar0 >> 1) & 3);
  const int ac1 = (aIdx1 & 3) ^ ((ar1 >> 1) & 3);
  const unsigned char* Ag0 = A + grow(ar0) * 768 + ac0 * 16;
  const unsigned char* Ag1 = A + grow(ar1) * 768 + ac1 * 16;
  const int bIdx = w * 64 + lane;
  const int brS = bIdx >> 2;
  const int bcS = (bIdx & 3) ^ ((brS >> 1) & 3);
  const signed char* Bg[4] = { Q0 + (size_t)(n0 + brS) * 768 + bcS * 16,
                               Q1 + (size_t)(n0 + brS) * 768 + bcS * 16,
                               Q2 + (size_t)(n0 + brS) * 768 + bcS * 16,
                               Q3 + (size_t)(n0 + brS) * 768 + bcS * 16 };

  int4v acc[4][4][2] = {};   // [plane][m][n]
  const int arow = wr * 64 + (lane & 15);
  const int clog = lane >> 4;

  gload_lds16(Ag0, smem + aIdx0 * 16);
  gload_lds16(Ag1, smem + aIdx1 * 16);
  #pragma unroll
  for (int p = 0; p < 4; ++p) gload_lds16(Bg[p], smem + 8192 + p * 4096 + bIdx * 16);
  __syncthreads();

  for (int kt = 0; kt < 12; ++kt) {
    if (kt < 11) {
      const int kn = (kt + 1) * 64;
      char* dst = smem + ((kt + 1) & 1) * 24576;
      gload_lds16(Ag0 + kn, dst + aIdx0 * 16);
      gload_lds16(Ag1 + kn, dst + aIdx1 * 16);
      #pragma unroll
      for (int p = 0; p < 4; ++p) gload_lds16(Bg[p] + kn, dst + 8192 + p * 4096 + bIdx * 16);
    }
    const signed char* ldsA = (const signed char*)smem + (kt & 1) * 24576;
    const signed char* ldsB = ldsA + 8192;
    int4v av[4], bv[2][4];
    #pragma unroll
    for (int m = 0; m < 4; ++m) {
      const int r = arow + m * 16;
      const int cp = clog ^ ((r >> 1) & 3);
      av[m] = *(const int4v*)(ldsA + r * 64 + cp * 16);
    }
    #pragma unroll
    for (int n = 0; n < 2; ++n) {
      const int r = wc * 32 + n * 16 + (lane & 15);
      const int cp = clog ^ ((r >> 1) & 3);
      #pragma unroll
      for (int p = 0; p < 4; ++p)
        bv[n][p] = *(const int4v*)(ldsB + p * 4096 + r * 64 + cp * 16);
    }
    #pragma unroll
    for (int p = 0; p < 4; ++p)
      #pragma unroll
      for (int m = 0; m < 4; ++m)
        #pragma unroll
        for (int n = 0; n < 2; ++n)
          acc[p][m][n] = __builtin_amdgcn_mfma_i32_16x16x64_i8(av[m], bv[n][p], acc[p][m][n], 0, 0, 0);
    __syncthreads();
  }

  // exact h (48-bit) into LDS as lo32 + hi16 (cross-wave handoff: __syncthreads only)
  unsigned int* smLo = (unsigned int*)smem;            // [128][64]
  short*        smHi = (short*)(smem + 32768);         // [128][64]
  #pragma unroll
  for (int m = 0; m < 4; ++m)
    #pragma unroll
    for (int n = 0; n < 2; ++n)
      #pragma unroll
      for (int r = 0; r < 4; ++r) {
        long long h = ((long long)acc[3][m][n][r] << 24) + ((long long)acc[2][m][n][r] << 16)
                    + ((long long)acc[1][m][n][r] << 8) + (long long)acc[0][m][n][r];
        const int rw = wr * 64 + m * 16 + clog * 4 + r;
        const int cl = wc * 32 + n * 16 + (lane & 15);
        smLo[rw * 64 + cl] = (unsigned int)h;
        smHi[rw * 64 + cl] = (short)(h >> 32);
      }
  __syncthreads();

  // fp64 LIF chains; thread: col = tid&63 (bank-conflict-free), j = (tid>>6)*8 + jj
  const int col = tid & 63;
  const int jgrp = tid >> 6;
  const int c = n0 + col;
  const double mn = mean[c], rs = rstd[c];
  const double gm = (double)gamma[c], bt = (double)beta[c];
  const int bI = by >> 1;
  const int l0 = (by & 1) * 32;
  unsigned int plo[4] = {0, 0, 0, 0}, phi[4] = {0, 0, 0, 0};
  #pragma unroll
  for (int jj = 0; jj < 8; ++jj) {
    const int j = jgrp * 8 + jj;
    double v = 0.;
    #pragma unroll
    for (int t = 0; t < 4; ++t) {
      const int rw = t * 32 + j;
      long long h = ((long long)smHi[rw * 64 + col] << 32) | (unsigned long long)smLo[rw * 64 + col];
      double g = ((double)h * INV33 - mn) * rs * gm + bt;
      v = v + (g - v) * 0.5;
      bool s = (v >= 1.0);
      if (s) { if (jj < 4) plo[t] |= 1u << (8 * jj); else phi[t] |= 1u << (8 * (jj - 4)); }
      v = s ? 0. : v;
    }
  }
  #pragma unroll
  for (int t = 0; t < 4; ++t) {
    ui2 wv; wv.x = plo[t]; wv.y = phi[t];
    *(ui2*)(s2 + (size_t)(t * 64 + bI) * HL_ + (size_t)c * 64 + l0 + jgrp * 8) = wv;
  }
}

// ---- GEMM2: exact i8 x 2 planes, safe dbuf; C fp32 + fp64 partial stats ----
__global__ __launch_bounds__(256) void k_gemm2(
    const signed char* __restrict__ A,
    const signed char* __restrict__ R0, const signed char* __restrict__ R1,
    float* __restrict__ C,
    double* __restrict__ partS, double* __restrict__ partQ) {
  __shared__ __align__(16) char smem[49152];   // 2 x (A 8KB + P0 8KB + P1 8KB)
  const int tid  = threadIdx.x;
  const int lane = tid & 63;
  const int w    = tid >> 6;
  const int wr = tid >> 7;
  const int wc = (tid >> 6) & 1;
  const int n0 = blockIdx.x * 128;
  const int by = blockIdx.y;

  const int i0 = w * 128 + lane;
  const int i1 = i0 + 64;
  const int r0s = i0 >> 2, r1s = i1 >> 2;
  const int c0s = (i0 & 3) ^ ((r0s >> 1) & 3);
  const int c1s = (i1 & 3) ^ ((r1s >> 1) & 3);
  const signed char* Ag0 = A + (size_t)(by * 128 + r0s) * 3072 + c0s * 16;
  const signed char* Ag1 = A + (size_t)(by * 128 + r1s) * 3072 + c1s * 16;
  const signed char* P0g0 = R0 + (size_t)(n0 + r0s) * 3072 + c0s * 16;
  const signed char* P0g1 = R0 + (size_t)(n0 + r1s) * 3072 + c1s * 16;
  const signed char* P1g0 = R1 + (size_t)(n0 + r0s) * 3072 + c0s * 16;
  const signed char* P1g1 = R1 + (size_t)(n0 + r1s) * 3072 + c1s * 16;

  int4v acc[2][4][4] = {};
  const int arow = wr * 64 + (lane & 15);
  const int brow = wc * 64 + (lane & 15);
  const int clog = lane >> 4;

  gload_lds16(Ag0, smem + i0 * 16);
  gload_lds16(Ag1, smem + i1 * 16);
  gload_lds16(P0g0, smem + 8192 + i0 * 16);
  gload_lds16(P0g1, smem + 8192 + i1 * 16);
  gload_lds16(P1g0, smem + 16384 + i0 * 16);
  gload_lds16(P1g1, smem + 16384 + i1 * 16);
  __syncthreads();

  for (int kt = 0; kt < 48; ++kt) {
    if (kt < 47) {
      const int kn = (kt + 1) * 64;
      char* dst = smem + ((kt + 1) & 1) * 24576;
      gload_lds16(Ag0 + kn, dst + i0 * 16);
      gload_lds16(Ag1 + kn, dst + i1 * 16);
      gload_lds16(P0g0 + kn, dst + 8192 + i0 * 16);
      gload_lds16(P0g1 + kn, dst + 8192 + i1 * 16);
      gload_lds16(P1g0 + kn, dst + 16384 + i0 * 16);
      gload_lds16(P1g1 + kn, dst + 16384 + i1 * 16);
    }
    const signed char* ldsA = (const signed char*)smem + (kt & 1) * 24576;
    int4v av[4], bv[2][4];
    #pragma unroll
    for (int m = 0; m < 4; ++m) {
      const int r = arow + m * 16;
      const int cp = clog ^ ((r >> 1) & 3);
      av[m] = *(const int4v*)(ldsA + r * 64 + cp * 16);
    }
    #pragma unroll
    for (int n = 0; n < 4; ++n) {
      const int r = brow + n * 16;
      const int cp = clog ^ ((r >> 1) & 3);
      bv[0][n] = *(const int4v*)(ldsA + 8192 + r * 64 + cp * 16);
      bv[1][n] = *(const int4v*)(ldsA + 16384 + r * 64 + cp * 16);
    }
    #pragma unroll
    for (int p = 0; p < 2; ++p)
      #pragma unroll
      for (int m = 0; m < 4; ++m)
        #pragma unroll
        for (int n = 0; n < 4; ++n)
          acc[p][m][n] = __builtin_amdgcn_mfma_i32_16x16x64_i8(av[m], bv[p][n], acc[p][m][n], 0, 0, 0);
    __syncthreads();
  }

  const int r0o = by * 128 + wr * 64 + (clog << 2);
  const int c0o = n0 + wc * 64 + (lane & 15);
  #pragma unroll
  for (int n = 0; n < 4; ++n) {
    double s = 0.0, q = 0.0;
    #pragma unroll
    for (int m = 0; m < 4; ++m)
      #pragma unroll
      for (int r = 0; r < 4; ++r) {
        int hv = acc[0][m][n][r] + 256 * acc[1][m][n][r];
        double h = (double)hv * (1.0 / 131072.0);
        C[(size_t)(r0o + m * 16 + r) * 768 + (c0o + n * 16)] = (float)h;
        s += h;
        q += h * h;
      }
    s += __shfl_xor(s, 16);
    q += __shfl_xor(q, 16);
    s += __shfl_xor(s, 32);
    q += __shfl_xor(q, 32);
    if (clog == 0) {
      int col = n0 + wc * 64 + n * 16 + lane;
      partS[(size_t)(by * 2 + wr) * D_ + col] = s;
      partQ[(size_t)(by * 2 + wr) * D_ + col] = q;
    }
  }
}

// ---- reduce 256 partials -> mean, rstd (fp64) ----
__global__ __launch_bounds__(256) void k_bnred(
    const double* __restrict__ pS, const double* __restrict__ pQ,
    double* __restrict__ mean, double* __restrict__ rstd, int N, double invM) {
  int i = blockIdx.x * 256 + threadIdx.x;
  if (i >= N) return;
  double s = 0.0, q = 0.0;
  for (int p = 0; p < 256; ++p) {
    s += pS[(size_t)p * N + i];
    q += pQ[(size_t)p * N + i];
  }
  double m = s * invM;
  double v = q * invM - m * m;
  mean[i] = m;
  rstd[i] = 1.0 / sqrt(v + 1e-5);
}

// ---- BN2-apply (fp64) + (L,D)->(D,L) per-tb transpose -> fp32 out ----
__global__ __launch_bounds__(256) void k_bn2apply(
    const float* __restrict__ O, const double* __restrict__ mean,
    const double* __restrict__ rstd, const float* __restrict__ gamma,
    const float* __restrict__ beta, float* __restrict__ out) {
  __shared__ __align__(16) float sm[64 * 65];
  const int tid = threadIdx.x;
  const int d0 = blockIdx.x * 64;
  const int tb = blockIdx.y;
  const int doff = tid & 63;
  const int lgrp = tid >> 6;
  const double mn = mean[d0 + doff];
  const double rs = rstd[d0 + doff];
  const double gm = (double)gamma[d0 + doff];
  const double bt = (double)beta[d0 + doff];
  #pragma unroll 4
  for (int p = 0; p < 16; ++p) {
    const int l = p * 4 + lgrp;
    double v = (double)O[((size_t)tb * 64 + l) * D_ + d0 + doff];
    sm[doff * 65 + l] = (float)(((v - mn) * rs) * gm + bt);
  }
  __syncthreads();
  const int l4 = (tid & 15) * 4;
  const int db = tid >> 4;
  #pragma unroll
  for (int p = 0; p < 4; ++p) {
    const int dd = p * 16 + db;
    f4 wv;
    wv.x = sm[dd * 65 + l4 + 0];
    wv.y = sm[dd * 65 + l4 + 1];
    wv.z = sm[dd * 65 + l4 + 2];
    wv.w = sm[dd * 65 + l4 + 3];
    *(f4*)(out + (size_t)tb * (D_ * L_) + (size_t)(d0 + dd) * 64 + l4) = wv;
  }
}

extern "C" void kernel_launch(void* const* d_in, const int* in_sizes, int n_in,
                              void* d_out, int out_size, void* d_ws, size_t ws_size,
                              hipStream_t stream) {
  const float* x      = (const float*)d_in[0];
  const float* W1     = (const float*)d_in[1];
  const float* gamma1 = (const float*)d_in[2];
  const float* beta1  = (const float*)d_in[3];
  const float* W2     = (const float*)d_in[4];
  const float* gamma2 = (const float*)d_in[5];
  const float* beta2  = (const float*)d_in[6];
  float* out = (float*)d_out;
  (void)in_sizes; (void)n_in; (void)out_size; (void)ws_size;

  // s1 (i8 spikes, 12.6 MB) lives in d_out; d_out is fully rewritten at the end.
  unsigned char* s1 = (unsigned char*)d_out;

  char* ws = (char*)d_ws;
  size_t off = 0;
  auto alloc = [&](size_t bytes) -> void* {
    void* p = ws + off;
    off += (bytes + 255) & ~(size_t)255;
    return p;
  };
  signed char* Q0 = (signed char*)alloc(NW_);
  signed char* Q1 = (signed char*)alloc(NW_);
  signed char* Q2 = (signed char*)alloc(NW_);
  signed char* Q3 = (signed char*)alloc(NW_);
  int* Qint       = (int*)alloc((size_t)NW_ * 4);                 // 9.4 MB
  signed char* R0 = (signed char*)alloc(NW_);
  signed char* R1 = (signed char*)alloc(NW_);
  unsigned char* s1T = (unsigned char*)alloc((size_t)768 * M1_);  // 12.6 MB
  int* Gpart      = (int*)alloc((size_t)8 * 768 * 768 * 4);       // 18.9 MB
  signed char* g0 = (signed char*)alloc((size_t)768 * 768);
  signed char* g1 = (signed char*)alloc((size_t)768 * 768);
  double* YT      = (double*)alloc((size_t)H_ * 768 * 8);         // 18.9 MB
  int* colsum     = (int*)alloc(768 * 4);
  signed char* s2 = (signed char*)alloc((size_t)M1_ * H_);        // 50.3 MB
  float* O2       = (float*)alloc((size_t)M1_ * D_ * 4);          // 50.3 MB
  double* pS2 = (double*)alloc((size_t)256 * D_ * 8);
  double* pQ2 = (double*)alloc((size_t)256 * D_ * 8);
  double* mean1 = (double*)alloc((size_t)H_ * 8);
  double* rstd1 = (double*)alloc((size_t)H_ * 8);
  double* mean2 = (double*)alloc((size_t)D_ * 8);
  double* rstd2 = (double*)alloc((size_t)D_ * 8);

  hipMemsetAsync(colsum, 0, 768 * 4, stream);
  k_convert<<<NW_ / 256, 256, 0, stream>>>(W1, W2, Q0, Q1, Q2, Q3, Qint, R0, R1);
  k_lif1<<<BLD_ / 4 / 256, 256, 0, stream>>>(x, s1);
  k_s1t<<<dim3(12, 64, 4), 256, 0, stream>>>(s1, s1T, colsum);
  k_gram<<<dim3(36, 8), 256, 0, stream>>>(s1T, Gpart);
  k_gramred<<<(768 * 768) / 256, 256, 0, stream>>>(Gpart, g0, g1);
  k_gq<<<dim3(12, 48), 256, 0, stream>>>(g0, g1, Q0, Q1, Q2, Q3, YT);
  k_stats1<<<H_, 256, 0, stream>>>(YT, Qint, colsum, mean1, rstd1);
  k_bnlif<<<dim3(H_ / 64, (B_ * L_) / 32), 256, 0, stream>>>(
      s1, Q0, Q1, Q2, Q3, mean1, rstd1, gamma1, beta1, s2);
  k_gemm2<<<dim3(D_ / 128, M1_ / 128), 256, 0, stream>>>(s2, R0, R1, O2, pS2, pQ2);
  k_bnred<<<(D_ + 255) / 256, 256, 0, stream>>>(pS2, pQ2, mean2, rstd2, D_, 1.0 / (double)M1_);
  k_bn2apply<<<dim3(D_ / 64, T_ * B_), 256, 0, stream>>>(O2, mean2, rstd2, gamma2, beta2, out);
}

// Round 8
// 404.365 us; speedup vs baseline: 1.7261x; 1.1704x over previous
//
#include <hip/hip_runtime.h>
#include <stdint.h>
#include <stddef.h>

#define T_ 4
#define B_ 64
#define L_ 64
#define D_ 768
#define H_ 3072
#define M1_ 16384      // T*B*L rows
#define BLD_ 3145728   // B*L*D
#define NW_ 2359296    // 3072*768
#define HL_ 196608     // H_*L_

using f4    = __attribute__((ext_vector_type(4))) float;
using int4v = __attribute__((ext_vector_type(4))) int;
using uc4   = __attribute__((ext_vector_type(4))) unsigned char;
using uc16  = __attribute__((ext_vector_type(16))) unsigned char;
using ui2   = __attribute__((ext_vector_type(2))) unsigned int;

static __device__ __forceinline__ void gload_lds16(const void* g, void* l) {
  __builtin_amdgcn_global_load_lds((const __attribute__((address_space(1))) void*)g,
                                   (__attribute__((address_space(3))) void*)l, 16, 0, 0);
}

#define INV33 (1.0/8589934592.0)

// ---- weights: W1 -> int32 q (scale 2^33, clamp 126*2^24) + 4 i8 digit planes;
// ----          W2 -> 2 i8 digit planes (scale 2^17, clamp 127*256)
__global__ __launch_bounds__(256) void k_convert(
    const float* __restrict__ W1, const float* __restrict__ W2,
    signed char* __restrict__ Q0, signed char* __restrict__ Q1,
    signed char* __restrict__ Q2, signed char* __restrict__ Q3,
    int* __restrict__ Qint,
    signed char* __restrict__ R0, signed char* __restrict__ R1) {
  int i = blockIdx.x * 256 + threadIdx.x;
  if (i >= NW_) return;
  {
    double w = (double)W1[i];
    long long q = llrint(w * 8589934592.0);
    if (q >  2113929216LL) q =  2113929216LL;
    if (q < -2113929216LL) q = -2113929216LL;
    int ii = (int)q;
    Qint[i] = ii;
    int b0 = ((ii + 128) & 255) - 128; ii = (ii - b0) >> 8;
    int b1 = ((ii + 128) & 255) - 128; ii = (ii - b1) >> 8;
    int b2 = ((ii + 128) & 255) - 128; ii = (ii - b2) >> 8;
    Q0[i] = (signed char)b0; Q1[i] = (signed char)b1;
    Q2[i] = (signed char)b2; Q3[i] = (signed char)ii;
  }
  {
    double w = (double)W2[i];
    long long q = llrint(w * 131072.0);
    if (q >  32512LL) q =  32512LL;
    if (q < -32512LL) q = -32512LL;
    int ii = (int)q;
    int b0 = ((ii + 128) & 255) - 128;
    R0[i] = (signed char)b0;
    R1[i] = (signed char)((ii - b0) >> 8);
  }
}

// ---- LIF1 in fp64, spikes as i8 {0,1} ----
__global__ __launch_bounds__(256) void k_lif1(const float* __restrict__ x,
                                              unsigned char* __restrict__ s1) {
  size_t i = ((size_t)blockIdx.x * 256 + threadIdx.x) * 4;
  double v0 = 0., v1 = 0., v2 = 0., v3 = 0.;
  #pragma unroll
  for (int t = 0; t < T_; ++t) {
    f4 xt = *(const f4*)(x + (size_t)t * BLD_ + i);
    v0 = v0 + ((double)xt.x - v0) * 0.5;
    v1 = v1 + ((double)xt.y - v1) * 0.5;
    v2 = v2 + ((double)xt.z - v2) * 0.5;
    v3 = v3 + ((double)xt.w - v3) * 0.5;
    uc4 s;
    s.x = (v0 >= 1.0) ? 1 : 0;
    s.y = (v1 >= 1.0) ? 1 : 0;
    s.z = (v2 >= 1.0) ? 1 : 0;
    s.w = (v3 >= 1.0) ? 1 : 0;
    *(uc4*)(s1 + (size_t)t * BLD_ + i) = s;
    v0 = s.x ? 0. : v0;
    v1 = s.y ? 0. : v1;
    v2 = s.z ? 0. : v2;
    v3 = s.w ? 0. : v3;
  }
}

// ---- transpose s1 (16384 x 768) -> s1T (768 x 16384), + column spike counts ----
// grid (12 dblk, 64 blblk, 4 t); s1T[d][t*4096 + bl]
__global__ __launch_bounds__(256) void k_s1t(const unsigned char* __restrict__ s1,
                                             unsigned char* __restrict__ sT,
                                             int* __restrict__ colsum) {
  __shared__ __align__(16) unsigned char sm[64 * 80];
  const int tid = threadIdx.x;
  const int d0 = blockIdx.x * 64;
  const int bl0 = blockIdx.y * 64;
  const int t = blockIdx.z;
  {
    const int i = tid >> 2, ch = tid & 3;
    uc16 v = *(const uc16*)(s1 + (size_t)t * BLD_ + (size_t)(bl0 + i) * 768 + d0 + ch * 16);
    *(uc16*)(sm + i * 80 + ch * 16) = v;
  }
  __syncthreads();
  {
    const int d = tid >> 2, oc = tid & 3;
    union { uc16 v; unsigned char b[16]; } u;
    int s = 0;
    #pragma unroll
    for (int jj = 0; jj < 16; ++jj) {
      unsigned char c = sm[(oc * 16 + jj) * 80 + d];
      u.b[jj] = c;
      s += c;
    }
    *(uc16*)(sT + (size_t)(d0 + d) * M1_ + t * 4096 + bl0 + oc * 16) = u.v;
    s += __shfl_xor(s, 1);
    s += __shfl_xor(s, 2);
    if ((tid & 3) == 0) atomicAdd(&colsum[d0 + d], s);
  }
}

// ---- Gram: G = S^T S (768x768 int), splitK partials. grid (36 tilepair, 8 ks) ----
__global__ __launch_bounds__(256, 2) void k_gram(const unsigned char* __restrict__ sT,
                                                 int* __restrict__ Gpart) {
  __shared__ __align__(16) char smem[32768];   // 2 x (A 8KB + B 8KB)
  const int tid = threadIdx.x;
  const int lane = tid & 63;
  const int wr = tid >> 7;
  const int wc = (tid >> 6) & 1;
  const int tr = blockIdx.x / 6, tc = blockIdx.x % 6;
  const int ks = blockIdx.y;
  const size_t m0 = (size_t)ks * 2048;

  const int s0 = tid, s1i = tid + 256;
  const int rA0 = s0 >> 2, rA1 = s1i >> 2;
  const int cA0 = (s0 & 3) ^ ((rA0 >> 1) & 3);
  const int cA1 = (s1i & 3) ^ ((rA1 >> 1) & 3);
  const unsigned char* Ag0 = sT + (size_t)(tr * 128 + rA0) * M1_ + m0 + cA0 * 16;
  const unsigned char* Ag1 = sT + (size_t)(tr * 128 + rA1) * M1_ + m0 + cA1 * 16;
  const unsigned char* Bg0 = sT + (size_t)(tc * 128 + rA0) * M1_ + m0 + cA0 * 16;
  const unsigned char* Bg1 = sT + (size_t)(tc * 128 + rA1) * M1_ + m0 + cA1 * 16;

  int4v acc[4][4] = {};
  const int clog = lane >> 4;

  gload_lds16(Ag0, smem + s0 * 16);
  gload_lds16(Ag1, smem + s1i * 16);
  gload_lds16(Bg0, smem + 8192 + s0 * 16);
  gload_lds16(Bg1, smem + 8192 + s1i * 16);
  __syncthreads();

  for (int kt = 0; kt < 32; ++kt) {
    if (kt < 31) {
      const int kn = (kt + 1) * 64;
      char* dst = smem + ((kt + 1) & 1) * 16384;
      gload_lds16(Ag0 + kn, dst + s0 * 16);
      gload_lds16(Ag1 + kn, dst + s1i * 16);
      gload_lds16(Bg0 + kn, dst + 8192 + s0 * 16);
      gload_lds16(Bg1 + kn, dst + 8192 + s1i * 16);
    }
    const signed char* ldsA = (const signed char*)smem + (kt & 1) * 16384;
    const signed char* ldsB = ldsA + 8192;
    int4v av[4], bv[4];
    #pragma unroll
    for (int m = 0; m < 4; ++m) {
      const int r = wr * 64 + m * 16 + (lane & 15);
      const int cp = clog ^ ((r >> 1) & 3);
      av[m] = *(const int4v*)(ldsA + r * 64 + cp * 16);
    }
    #pragma unroll
    for (int n = 0; n < 4; ++n) {
      const int r = wc * 64 + n * 16 + (lane & 15);
      const int cp = clog ^ ((r >> 1) & 3);
      bv[n] = *(const int4v*)(ldsB + r * 64 + cp * 16);
    }
    #pragma unroll
    for (int m = 0; m < 4; ++m)
      #pragma unroll
      for (int n = 0; n < 4; ++n)
        acc[m][n] = __builtin_amdgcn_mfma_i32_16x16x64_i8(av[m], bv[n], acc[m][n], 0, 0, 0);
    __syncthreads();
  }

  const int r0 = tr * 128 + wr * 64 + (clog << 2);
  const int c0 = tc * 128 + wc * 64 + (lane & 15);
  #pragma unroll
  for (int m = 0; m < 4; ++m)
    #pragma unroll
    for (int n = 0; n < 4; ++n)
      #pragma unroll
      for (int rr = 0; rr < 4; ++rr)
        Gpart[((size_t)ks * 768 + r0 + m * 16 + rr) * 768 + c0 + n * 16] = acc[m][n][rr];
}

// ---- reduce 8 Gram partials -> 2 i8 digit planes (G = g0 + 256*g1, G<=16384) ----
__global__ __launch_bounds__(256) void k_gramred(const int* __restrict__ Gpart,
                                                 signed char* __restrict__ g0,
                                                 signed char* __restrict__ g1) {
  int i = blockIdx.x * 256 + threadIdx.x;
  if (i >= 768 * 768) return;
  int G = 0;
  #pragma unroll
  for (int ks = 0; ks < 8; ++ks) G += Gpart[(size_t)ks * 768 * 768 + i];
  int b0 = ((G + 128) & 255) - 128;
  g0[i] = (signed char)b0;
  g1[i] = (signed char)((G - b0) >> 8);
}

// ---- Y = G * Q  (exact via 2x4 i8 plane pairs, fp64 fold), YT[c][k] ----
// tile 64k x 64c, 4 waves (wave w -> k rows w*16..+15). grid (12, 48)
__global__ __launch_bounds__(256, 2) void k_gq(
    const signed char* __restrict__ g0, const signed char* __restrict__ g1,
    const signed char* __restrict__ Q0, const signed char* __restrict__ Q1,
    const signed char* __restrict__ Q2, const signed char* __restrict__ Q3,
    double* __restrict__ YT) {
  __shared__ __align__(16) char smem[49152];   // 2 x (A0 4K | A1 4K | B0..B3 16K)
  const int tid = threadIdx.x;
  const int lane = tid & 63;
  const int w = tid >> 6;
  const int k0 = blockIdx.x * 64;
  const int c0 = blockIdx.y * 64;

  const int row = tid >> 2;
  const int ch = (tid & 3) ^ ((row >> 1) & 3);
  const signed char* Ag[2] = { g0 + (size_t)(k0 + row) * 768 + ch * 16,
                               g1 + (size_t)(k0 + row) * 768 + ch * 16 };
  const signed char* Bg[4] = { Q0 + (size_t)(c0 + row) * 768 + ch * 16,
                               Q1 + (size_t)(c0 + row) * 768 + ch * 16,
                               Q2 + (size_t)(c0 + row) * 768 + ch * 16,
                               Q3 + (size_t)(c0 + row) * 768 + ch * 16 };

  int4v acc[8][4] = {};   // [a*4+p][n]
  const int clog = lane >> 4;

  #pragma unroll
  for (int a = 0; a < 2; ++a) gload_lds16(Ag[a], smem + a * 4096 + tid * 16);
  #pragma unroll
  for (int p = 0; p < 4; ++p) gload_lds16(Bg[p], smem + 8192 + p * 4096 + tid * 16);
  __syncthreads();

  for (int kt = 0; kt < 12; ++kt) {
    if (kt < 11) {
      const int kn = (kt + 1) * 64;
      char* dst = smem + ((kt + 1) & 1) * 24576;
      #pragma unroll
      for (int a = 0; a < 2; ++a) gload_lds16(Ag[a] + kn, dst + a * 4096 + tid * 16);
      #pragma unroll
      for (int p = 0; p < 4; ++p) gload_lds16(Bg[p] + kn, dst + 8192 + p * 4096 + tid * 16);
    }
    const signed char* base = (const signed char*)smem + (kt & 1) * 24576;
    const int ar = w * 16 + (lane & 15);
    const int acp = clog ^ ((ar >> 1) & 3);
    int4v av[2];
    #pragma unroll
    for (int a = 0; a < 2; ++a)
      av[a] = *(const int4v*)(base + a * 4096 + ar * 64 + acp * 16);
    #pragma unroll
    for (int p = 0; p < 4; ++p) {
      int4v bv[4];
      #pragma unroll
      for (int n = 0; n < 4; ++n) {
        const int br = n * 16 + (lane & 15);
        const int bcp = clog ^ ((br >> 1) & 3);
        bv[n] = *(const int4v*)(base + 8192 + p * 4096 + br * 64 + bcp * 16);
      }
      #pragma unroll
      for (int a = 0; a < 2; ++a)
        #pragma unroll
        for (int n = 0; n < 4; ++n)
          acc[a * 4 + p][n] = __builtin_amdgcn_mfma_i32_16x16x64_i8(av[a], bv[n], acc[a * 4 + p][n], 0, 0, 0);
    }
    __syncthreads();
  }

  #pragma unroll
  for (int n = 0; n < 4; ++n)
    #pragma unroll
    for (int r = 0; r < 4; ++r) {
      int A0 = acc[0][n][r] + (acc[4][n][r] << 8);
      int A1 = acc[1][n][r] + (acc[5][n][r] << 8);
      int A2 = acc[2][n][r] + (acc[6][n][r] << 8);
      int A3 = acc[3][n][r] + (acc[7][n][r] << 8);
      double Y = (double)A0 + 256.0 * (double)A1 + 65536.0 * (double)A2 + 16777216.0 * (double)A3;
      const int k = k0 + w * 16 + clog * 4 + r;
      const int c = c0 + n * 16 + (lane & 15);
      YT[(size_t)c * 768 + k] = Y;
    }
}

// ---- BN1 stats: mean_c = colsum.q_c/(M*2^33); E[h^2]_c = q_c.Y_c/(M*2^66) ----
__global__ __launch_bounds__(256) void k_stats1(
    const double* __restrict__ YT, const int* __restrict__ Qint,
    const int* __restrict__ colsum,
    double* __restrict__ mean, double* __restrict__ rstd) {
  __shared__ double red[8];
  const int c = blockIdx.x;
  const int tid = threadIdx.x;
  double s2 = 0.0, sm = 0.0;
  for (int k = tid; k < 768; k += 256) {
    double q = (double)Qint[(size_t)c * 768 + k];
    s2 += q * YT[(size_t)c * 768 + k];
    sm += q * (double)colsum[k];
  }
  #pragma unroll
  for (int o = 32; o; o >>= 1) { s2 += __shfl_xor(s2, o); sm += __shfl_xor(sm, o); }
  if ((tid & 63) == 0) { red[(tid >> 6) * 2] = s2; red[(tid >> 6) * 2 + 1] = sm; }
  __syncthreads();
  if (tid == 0) {
    double S2 = red[0] + red[2] + red[4] + red[6];
    double SM = red[1] + red[3] + red[5] + red[7];
    double mn = SM * INV33 * (1.0 / 16384.0);
    double Eh2 = S2 * INV33 * INV33 * (1.0 / 16384.0);
    double var = Eh2 - mn * mn;
    mean[c] = mn;
    rstd[c] = 1.0 / sqrt(var + 1e-5);
  }
}

// ---- GEMM1 + BN1-apply + fp64 LIF2 + transposed i8 spike write ----
// tile 128m x 64n (m rows: t*4096 + by*32 + j), safe dbuf, 48KB LDS.
// __launch_bounds__(256,2): keep VGPR+AGPR <= 256/wave (r7: 132+128=260 -> 1 wave/SIMD cliff)
__global__ __launch_bounds__(256, 2) void k_bnlif(
    const unsigned char* __restrict__ A,
    const signed char* __restrict__ Q0, const signed char* __restrict__ Q1,
    const signed char* __restrict__ Q2, const signed char* __restrict__ Q3,
    const double* __restrict__ mean, const double* __restrict__ rstd,
    const float* __restrict__ gamma, const float* __restrict__ beta,
    signed char* __restrict__ s2) {
  __shared__ __align__(16) char smem[49152];   // 2 x (A 8KB + B 16KB) ; epilogue lo32/hi16 overlay
  const int tid  = threadIdx.x;
  const int lane = tid & 63;
  const int w    = tid >> 6;
  const int wr = tid >> 7;
  const int wc = (tid >> 6) & 1;
  const int n0 = blockIdx.x * 64;
  const int by = blockIdx.y;

  auto grow = [&](int r) -> size_t {
    return (size_t)4096 * (r >> 5) + (size_t)by * 32 + (r & 31);
  };
  const int aIdx0 = w * 128 + lane;
  const int aIdx1 = aIdx0 + 64;
  const int ar0 = aIdx0 >> 2, ar1 = aIdx1 >> 2;
  const int ac0 = (aIdx0 & 3) ^ ((ar0 >> 1) & 3);
  const int ac1 = (aIdx1 & 3) ^ ((ar1 >> 1) & 3);
  const unsigned char* Ag0 = A + grow(ar0) * 768 + ac0 * 16;
  const unsigned char* Ag1 = A + grow(ar1) * 768 + ac1 * 16;
  const int bIdx = w * 64 + lane;
  const int brS = bIdx >> 2;
  const int bcS = (bIdx & 3) ^ ((brS >> 1) & 3);
  const signed char* Bg[4] = { Q0 + (size_t)(n0 + brS) * 768 + bcS * 16,
                               Q1 + (size_t)(n0 + brS) * 768 + bcS * 16,
                               Q2 + (size_t)(n0 + brS) * 768 + bcS * 16,
                               Q3 + (size_t)(n0 + brS) * 768 + bcS * 16 };

  int4v acc[4][4][2] = {};   // [plane][m][n]
  const int arow = wr * 64 + (lane & 15);
  const int clog = lane >> 4;

  gload_lds16(Ag0, smem + aIdx0 * 16);
  gload_lds16(Ag1, smem + aIdx1 * 16);
  #pragma unroll
  for (int p = 0; p < 4; ++p) gload_lds16(Bg[p], smem + 8192 + p * 4096 + bIdx * 16);
  __syncthreads();

  for (int kt = 0; kt < 12; ++kt) {
    if (kt < 11) {
      const int kn = (kt + 1) * 64;
      char* dst = smem + ((kt + 1) & 1) * 24576;
      gload_lds16(Ag0 + kn, dst + aIdx0 * 16);
      gload_lds16(Ag1 + kn, dst + aIdx1 * 16);
      #pragma unroll
      for (int p = 0; p < 4; ++p) gload_lds16(Bg[p] + kn, dst + 8192 + p * 4096 + bIdx * 16);
    }
    const signed char* ldsA = (const signed char*)smem + (kt & 1) * 24576;
    const signed char* ldsB = ldsA + 8192;
    int4v av[4], bv[2][4];
    #pragma unroll
    for (int m = 0; m < 4; ++m) {
      const int r = arow + m * 16;
      const int cp = clog ^ ((r >> 1) & 3);
      av[m] = *(const int4v*)(ldsA + r * 64 + cp * 16);
    }
    #pragma unroll
    for (int n = 0; n < 2; ++n) {
      const int r = wc * 32 + n * 16 + (lane & 15);
      const int cp = clog ^ ((r >> 1) & 3);
      #pragma unroll
      for (int p = 0; p < 4; ++p)
        bv[n][p] = *(const int4v*)(ldsB + p * 4096 + r * 64 + cp * 16);
    }
    #pragma unroll
    for (int p = 0; p < 4; ++p)
      #pragma unroll
      for (int m = 0; m < 4; ++m)
        #pragma unroll
        for (int n = 0; n < 2; ++n)
          acc[p][m][n] = __builtin_amdgcn_mfma_i32_16x16x64_i8(av[m], bv[n][p], acc[p][m][n], 0, 0, 0);
    __syncthreads();
  }

  // exact h (48-bit) into LDS as lo32 + hi16 (cross-wave handoff: __syncthreads only)
  unsigned int* smLo = (unsigned int*)smem;            // [128][64]
  short*        smHi = (short*)(smem + 32768);         // [128][64]
  #pragma unroll
  for (int m = 0; m < 4; ++m)
    #pragma unroll
    for (int n = 0; n < 2; ++n)
      #pragma unroll
      for (int r = 0; r < 4; ++r) {
        long long h = ((long long)acc[3][m][n][r] << 24) + ((long long)acc[2][m][n][r] << 16)
                    + ((long long)acc[1][m][n][r] << 8) + (long long)acc[0][m][n][r];
        const int rw = wr * 64 + m * 16 + clog * 4 + r;
        const int cl = wc * 32 + n * 16 + (lane & 15);
        smLo[rw * 64 + cl] = (unsigned int)h;
        smHi[rw * 64 + cl] = (short)(h >> 32);
      }
  __syncthreads();

  // fp64 LIF chains; thread: col = tid&63 (bank-conflict-free), j = (tid>>6)*8 + jj
  const int col = tid & 63;
  const int jgrp = tid >> 6;
  const int c = n0 + col;
  const double mn = mean[c], rs = rstd[c];
  const double gm = (double)gamma[c], bt = (double)beta[c];
  const int bI = by >> 1;
  const int l0 = (by & 1) * 32;
  unsigned int plo[4] = {0, 0, 0, 0}, phi[4] = {0, 0, 0, 0};
  #pragma unroll
  for (int jj = 0; jj < 8; ++jj) {
    const int j = jgrp * 8 + jj;
    double v = 0.;
    #pragma unroll
    for (int t = 0; t < 4; ++t) {
      const int rw = t * 32 + j;
      long long h = ((long long)smHi[rw * 64 + col] << 32) | (unsigned long long)smLo[rw * 64 + col];
      double g = ((double)h * INV33 - mn) * rs * gm + bt;
      v = v + (g - v) * 0.5;
      bool s = (v >= 1.0);
      if (s) { if (jj < 4) plo[t] |= 1u << (8 * jj); else phi[t] |= 1u << (8 * (jj - 4)); }
      v = s ? 0. : v;
    }
  }
  #pragma unroll
  for (int t = 0; t < 4; ++t) {
    ui2 wv; wv.x = plo[t]; wv.y = phi[t];
    *(ui2*)(s2 + (size_t)(t * 64 + bI) * HL_ + (size_t)c * 64 + l0 + jgrp * 8) = wv;
  }
}

// ---- GEMM2: exact i8 x 2 planes, safe dbuf; C fp32 + fp64 partial stats ----
__global__ __launch_bounds__(256, 2) void k_gemm2(
    const signed char* __restrict__ A,
    const signed char* __restrict__ R0, const signed char* __restrict__ R1,
    float* __restrict__ C,
    double* __restrict__ partS, double* __restrict__ partQ) {
  __shared__ __align__(16) char smem[49152];   // 2 x (A 8KB + P0 8KB + P1 8KB)
  const int tid  = threadIdx.x;
  const int lane = tid & 63;
  const int w    = tid >> 6;
  const int wr = tid >> 7;
  const int wc = (tid >> 6) & 1;
  const int n0 = blockIdx.x * 128;
  const int by = blockIdx.y;

  const int i0 = w * 128 + lane;
  const int i1 = i0 + 64;
  const int r0s = i0 >> 2, r1s = i1 >> 2;
  const int c0s = (i0 & 3) ^ ((r0s >> 1) & 3);
  const int c1s = (i1 & 3) ^ ((r1s >> 1) & 3);
  const signed char* Ag0 = A + (size_t)(by * 128 + r0s) * 3072 + c0s * 16;
  const signed char* Ag1 = A + (size_t)(by * 128 + r1s) * 3072 + c1s * 16;
  const signed char* P0g0 = R0 + (size_t)(n0 + r0s) * 3072 + c0s * 16;
  const signed char* P0g1 = R0 + (size_t)(n0 + r1s) * 3072 + c1s * 16;
  const signed char* P1g0 = R1 + (size_t)(n0 + r0s) * 3072 + c0s * 16;
  const signed char* P1g1 = R1 + (size_t)(n0 + r1s) * 3072 + c1s * 16;

  int4v acc[2][4][4] = {};
  const int arow = wr * 64 + (lane & 15);
  const int brow = wc * 64 + (lane & 15);
  const int clog = lane >> 4;

  gload_lds16(Ag0, smem + i0 * 16);
  gload_lds16(Ag1, smem + i1 * 16);
  gload_lds16(P0g0, smem + 8192 + i0 * 16);
  gload_lds16(P0g1, smem + 8192 + i1 * 16);
  gload_lds16(P1g0, smem + 16384 + i0 * 16);
  gload_lds16(P1g1, smem + 16384 + i1 * 16);
  __syncthreads();

  for (int kt = 0; kt < 48; ++kt) {
    if (kt < 47) {
      const int kn = (kt + 1) * 64;
      char* dst = smem + ((kt + 1) & 1) * 24576;
      gload_lds16(Ag0 + kn, dst + i0 * 16);
      gload_lds16(Ag1 + kn, dst + i1 * 16);
      gload_lds16(P0g0 + kn, dst + 8192 + i0 * 16);
      gload_lds16(P0g1 + kn, dst + 8192 + i1 * 16);
      gload_lds16(P1g0 + kn, dst + 16384 + i0 * 16);
      gload_lds16(P1g1 + kn, dst + 16384 + i1 * 16);
    }
    const signed char* ldsA = (const signed char*)smem + (kt & 1) * 24576;
    int4v av[4], bv[2][4];
    #pragma unroll
    for (int m = 0; m < 4; ++m) {
      const int r = arow + m * 16;
      const int cp = clog ^ ((r >> 1) & 3);
      av[m] = *(const int4v*)(ldsA + r * 64 + cp * 16);
    }
    #pragma unroll
    for (int n = 0; n < 4; ++n) {
      const int r = brow + n * 16;
      const int cp = clog ^ ((r >> 1) & 3);
      bv[0][n] = *(const int4v*)(ldsA + 8192 + r * 64 + cp * 16);
      bv[1][n] = *(const int4v*)(ldsA + 16384 + r * 64 + cp * 16);
    }
    #pragma unroll
    for (int p = 0; p < 2; ++p)
      #pragma unroll
      for (int m = 0; m < 4; ++m)
        #pragma unroll
        for (int n = 0; n < 4; ++n)
          acc[p][m][n] = __builtin_amdgcn_mfma_i32_16x16x64_i8(av[m], bv[p][n], acc[p][m][n], 0, 0, 0);
    __syncthreads();
  }

  const int r0o = by * 128 + wr * 64 + (clog << 2);
  const int c0o = n0 + wc * 64 + (lane & 15);
  #pragma unroll
  for (int n = 0; n < 4; ++n) {
    double s = 0.0, q = 0.0;
    #pragma unroll
    for (int m = 0; m < 4; ++m)
      #pragma unroll
      for (int r = 0; r < 4; ++r) {
        int hv = acc[0][m][n][r] + 256 * acc[1][m][n][r];
        double h = (double)hv * (1.0 / 131072.0);
        C[(size_t)(r0o + m * 16 + r) * 768 + (c0o + n * 16)] = (float)h;
        s += h;
        q += h * h;
      }
    s += __shfl_xor(s, 16);
    q += __shfl_xor(q, 16);
    s += __shfl_xor(s, 32);
    q += __shfl_xor(q, 32);
    if (clog == 0) {
      int col = n0 + wc * 64 + n * 16 + lane;
      partS[(size_t)(by * 2 + wr) * D_ + col] = s;
      partQ[(size_t)(by * 2 + wr) * D_ + col] = q;
    }
  }
}

// ---- reduce 256 partials -> mean, rstd (fp64) ----
__global__ __launch_bounds__(256) void k_bnred(
    const double* __restrict__ pS, const double* __restrict__ pQ,
    double* __restrict__ mean, double* __restrict__ rstd, int N, double invM) {
  int i = blockIdx.x * 256 + threadIdx.x;
  if (i >= N) return;
  double s = 0.0, q = 0.0;
  for (int p = 0; p < 256; ++p) {
    s += pS[(size_t)p * N + i];
    q += pQ[(size_t)p * N + i];
  }
  double m = s * invM;
  double v = q * invM - m * m;
  mean[i] = m;
  rstd[i] = 1.0 / sqrt(v + 1e-5);
}

// ---- BN2-apply (fp64) + (L,D)->(D,L) per-tb transpose -> fp32 out ----
__global__ __launch_bounds__(256) void k_bn2apply(
    const float* __restrict__ O, const double* __restrict__ mean,
    const double* __restrict__ rstd, const float* __restrict__ gamma,
    const float* __restrict__ beta, float* __restrict__ out) {
  __shared__ __align__(16) float sm[64 * 65];
  const int tid = threadIdx.x;
  const int d0 = blockIdx.x * 64;
  const int tb = blockIdx.y;
  const int doff = tid & 63;
  const int lgrp = tid >> 6;
  const double mn = mean[d0 + doff];
  const double rs = rstd[d0 + doff];
  const double gm = (double)gamma[d0 + doff];
  const double bt = (double)beta[d0 + doff];
  #pragma unroll 4
  for (int p = 0; p < 16; ++p) {
    const int l = p * 4 + lgrp;
    double v = (double)O[((size_t)tb * 64 + l) * D_ + d0 + doff];
    sm[doff * 65 + l] = (float)(((v - mn) * rs) * gm + bt);
  }
  __syncthreads();
  const int l4 = (tid & 15) * 4;
  const int db = tid >> 4;
  #pragma unroll
  for (int p = 0; p < 4; ++p) {
    const int dd = p * 16 + db;
    f4 wv;
    wv.x = sm[dd * 65 + l4 + 0];
    wv.y = sm[dd * 65 + l4 + 1];
    wv.z = sm[dd * 65 + l4 + 2];
    wv.w = sm[dd * 65 + l4 + 3];
    *(f4*)(out + (size_t)tb * (D_ * L_) + (size_t)(d0 + dd) * 64 + l4) = wv;
  }
}

extern "C" void kernel_launch(void* const* d_in, const int* in_sizes, int n_in,
                              void* d_out, int out_size, void* d_ws, size_t ws_size,
                              hipStream_t stream) {
  const float* x      = (const float*)d_in[0];
  const float* W1     = (const float*)d_in[1];
  const float* gamma1 = (const float*)d_in[2];
  const float* beta1  = (const float*)d_in[3];
  const float* W2     = (const float*)d_in[4];
  const float* gamma2 = (const float*)d_in[5];
  const float* beta2  = (const float*)d_in[6];
  float* out = (float*)d_out;
  (void)in_sizes; (void)n_in; (void)out_size; (void)ws_size;

  // s1 (i8 spikes, 12.6 MB) lives in d_out; d_out is fully rewritten at the end.
  unsigned char* s1 = (unsigned char*)d_out;

  char* ws = (char*)d_ws;
  size_t off = 0;
  auto alloc = [&](size_t bytes) -> void* {
    void* p = ws + off;
    off += (bytes + 255) & ~(size_t)255;
    return p;
  };
  signed char* Q0 = (signed char*)alloc(NW_);
  signed char* Q1 = (signed char*)alloc(NW_);
  signed char* Q2 = (signed char*)alloc(NW_);
  signed char* Q3 = (signed char*)alloc(NW_);
  int* Qint       = (int*)alloc((size_t)NW_ * 4);                 // 9.4 MB
  signed char* R0 = (signed char*)alloc(NW_);
  signed char* R1 = (signed char*)alloc(NW_);
  unsigned char* s1T = (unsigned char*)alloc((size_t)768 * M1_);  // 12.6 MB
  int* Gpart      = (int*)alloc((size_t)8 * 768 * 768 * 4);       // 18.9 MB
  signed char* g0 = (signed char*)alloc((size_t)768 * 768);
  signed char* g1 = (signed char*)alloc((size_t)768 * 768);
  double* YT      = (double*)alloc((size_t)H_ * 768 * 8);         // 18.9 MB
  int* colsum     = (int*)alloc(768 * 4);
  signed char* s2 = (signed char*)alloc((size_t)M1_ * H_);        // 50.3 MB
  float* O2       = (float*)alloc((size_t)M1_ * D_ * 4);          // 50.3 MB
  double* pS2 = (double*)alloc((size_t)256 * D_ * 8);
  double* pQ2 = (double*)alloc((size_t)256 * D_ * 8);
  double* mean1 = (double*)alloc((size_t)H_ * 8);
  double* rstd1 = (double*)alloc((size_t)H_ * 8);
  double* mean2 = (double*)alloc((size_t)D_ * 8);
  double* rstd2 = (double*)alloc((size_t)D_ * 8);

  hipMemsetAsync(colsum, 0, 768 * 4, stream);
  k_convert<<<NW_ / 256, 256, 0, stream>>>(W1, W2, Q0, Q1, Q2, Q3, Qint, R0, R1);
  k_lif1<<<BLD_ / 4 / 256, 256, 0, stream>>>(x, s1);
  k_s1t<<<dim3(12, 64, 4), 256, 0, stream>>>(s1, s1T, colsum);
  k_gram<<<dim3(36, 8), 256, 0, stream>>>(s1T, Gpart);
  k_gramred<<<(768 * 768) / 256, 256, 0, stream>>>(Gpart, g0, g1);
  k_gq<<<dim3(12, 48), 256, 0, stream>>>(g0, g1, Q0, Q1, Q2, Q3, YT);
  k_stats1<<<H_, 256, 0, stream>>>(YT, Qint, colsum, mean1, rstd1);
  k_bnlif<<<dim3(H_ / 64, (B_ * L_) / 32), 256, 0, stream>>>(
      s1, Q0, Q1, Q2, Q3, mean1, rstd1, gamma1, beta1, s2);
  k_gemm2<<<dim3(D_ / 128, M1_ / 128), 256, 0, stream>>>(s2, R0, R1, O2, pS2, pQ2);
  k_bnred<<<(D_ + 255) / 256, 256, 0, stream>>>(pS2, pQ2, mean2, rstd2, D_, 1.0 / (double)M1_);
  k_bn2apply<<<dim3(D_ / 64, T_ * B_), 256, 0, stream>>>(O2, mean2, rstd2, gamma2, beta2, out);
}

// Round 9
// 380.229 us; speedup vs baseline: 1.8357x; 1.0635x over previous
//
#include <hip/hip_runtime.h>
#include <stdint.h>
#include <stddef.h>

#define T_ 4
#define B_ 64
#define L_ 64
#define D_ 768
#define H_ 3072
#define M1_ 16384      // T*B*L rows
#define BLD_ 3145728   // B*L*D
#define NW_ 2359296    // 3072*768
#define HL_ 196608     // H_*L_

using f4    = __attribute__((ext_vector_type(4))) float;
using int4v = __attribute__((ext_vector_type(4))) int;
using uc4   = __attribute__((ext_vector_type(4))) unsigned char;
using uc16  = __attribute__((ext_vector_type(16))) unsigned char;
using ui2   = __attribute__((ext_vector_type(2))) unsigned int;

static __device__ __forceinline__ void gload_lds16(const void* g, void* l) {
  __builtin_amdgcn_global_load_lds((const __attribute__((address_space(1))) void*)g,
                                   (__attribute__((address_space(3))) void*)l, 16, 0, 0);
}

#define SGB() __builtin_amdgcn_sched_barrier(0)
#define HWBAR() __builtin_amdgcn_s_barrier()

#define INV33 (1.0/8589934592.0)

// ---- weights: W1 -> int32 q (scale 2^33, clamp 126*2^24) + 4 i8 digit planes;
// ----          W2 -> 2 i8 digit planes (scale 2^17, clamp 127*256)
__global__ __launch_bounds__(256) void k_convert(
    const float* __restrict__ W1, const float* __restrict__ W2,
    signed char* __restrict__ Q0, signed char* __restrict__ Q1,
    signed char* __restrict__ Q2, signed char* __restrict__ Q3,
    int* __restrict__ Qint,
    signed char* __restrict__ R0, signed char* __restrict__ R1) {
  int i = blockIdx.x * 256 + threadIdx.x;
  if (i >= NW_) return;
  {
    double w = (double)W1[i];
    long long q = llrint(w * 8589934592.0);
    if (q >  2113929216LL) q =  2113929216LL;
    if (q < -2113929216LL) q = -2113929216LL;
    int ii = (int)q;
    Qint[i] = ii;
    int b0 = ((ii + 128) & 255) - 128; ii = (ii - b0) >> 8;
    int b1 = ((ii + 128) & 255) - 128; ii = (ii - b1) >> 8;
    int b2 = ((ii + 128) & 255) - 128; ii = (ii - b2) >> 8;
    Q0[i] = (signed char)b0; Q1[i] = (signed char)b1;
    Q2[i] = (signed char)b2; Q3[i] = (signed char)ii;
  }
  {
    double w = (double)W2[i];
    long long q = llrint(w * 131072.0);
    if (q >  32512LL) q =  32512LL;
    if (q < -32512LL) q = -32512LL;
    int ii = (int)q;
    int b0 = ((ii + 128) & 255) - 128;
    R0[i] = (signed char)b0;
    R1[i] = (signed char)((ii - b0) >> 8);
  }
}

// ---- LIF1 in fp64, spikes as i8 {0,1} ----
__global__ __launch_bounds__(256) void k_lif1(const float* __restrict__ x,
                                              unsigned char* __restrict__ s1) {
  size_t i = ((size_t)blockIdx.x * 256 + threadIdx.x) * 4;
  double v0 = 0., v1 = 0., v2 = 0., v3 = 0.;
  #pragma unroll
  for (int t = 0; t < T_; ++t) {
    f4 xt = *(const f4*)(x + (size_t)t * BLD_ + i);
    v0 = v0 + ((double)xt.x - v0) * 0.5;
    v1 = v1 + ((double)xt.y - v1) * 0.5;
    v2 = v2 + ((double)xt.z - v2) * 0.5;
    v3 = v3 + ((double)xt.w - v3) * 0.5;
    uc4 s;
    s.x = (v0 >= 1.0) ? 1 : 0;
    s.y = (v1 >= 1.0) ? 1 : 0;
    s.z = (v2 >= 1.0) ? 1 : 0;
    s.w = (v3 >= 1.0) ? 1 : 0;
    *(uc4*)(s1 + (size_t)t * BLD_ + i) = s;
    v0 = s.x ? 0. : v0;
    v1 = s.y ? 0. : v1;
    v2 = s.z ? 0. : v2;
    v3 = s.w ? 0. : v3;
  }
}

// ---- transpose s1 (16384 x 768) -> s1T (768 x 16384), + column spike counts ----
__global__ __launch_bounds__(256) void k_s1t(const unsigned char* __restrict__ s1,
                                             unsigned char* __restrict__ sT,
                                             int* __restrict__ colsum) {
  __shared__ __align__(16) unsigned char sm[64 * 80];
  const int tid = threadIdx.x;
  const int d0 = blockIdx.x * 64;
  const int bl0 = blockIdx.y * 64;
  const int t = blockIdx.z;
  {
    const int i = tid >> 2, ch = tid & 3;
    uc16 v = *(const uc16*)(s1 + (size_t)t * BLD_ + (size_t)(bl0 + i) * 768 + d0 + ch * 16);
    *(uc16*)(sm + i * 80 + ch * 16) = v;
  }
  __syncthreads();
  {
    const int d = tid >> 2, oc = tid & 3;
    union { uc16 v; unsigned char b[16]; } u;
    int s = 0;
    #pragma unroll
    for (int jj = 0; jj < 16; ++jj) {
      unsigned char c = sm[(oc * 16 + jj) * 80 + d];
      u.b[jj] = c;
      s += c;
    }
    *(uc16*)(sT + (size_t)(d0 + d) * M1_ + t * 4096 + bl0 + oc * 16) = u.v;
    s += __shfl_xor(s, 1);
    s += __shfl_xor(s, 2);
    if ((tid & 3) == 0) atomicAdd(&colsum[d0 + d], s);
  }
}

// ---- Gram: G = S^T S (768x768 int), splitK partials. grid (36 tilepair, 8 ks) ----
__global__ __launch_bounds__(256, 2) void k_gram(const unsigned char* __restrict__ sT,
                                                 int* __restrict__ Gpart) {
  __shared__ __align__(16) char smem[32768];   // 2 x (A 8KB + B 8KB)
  const int tid = threadIdx.x;
  const int lane = tid & 63;
  const int wr = tid >> 7;
  const int wc = (tid >> 6) & 1;
  const int tr = blockIdx.x / 6, tc = blockIdx.x % 6;
  const int ks = blockIdx.y;
  const size_t m0 = (size_t)ks * 2048;

  const int s0 = tid, s1i = tid + 256;
  const int rA0 = s0 >> 2, rA1 = s1i >> 2;
  const int cA0 = (s0 & 3) ^ ((rA0 >> 1) & 3);
  const int cA1 = (s1i & 3) ^ ((rA1 >> 1) & 3);
  const unsigned char* Ag0 = sT + (size_t)(tr * 128 + rA0) * M1_ + m0 + cA0 * 16;
  const unsigned char* Ag1 = sT + (size_t)(tr * 128 + rA1) * M1_ + m0 + cA1 * 16;
  const unsigned char* Bg0 = sT + (size_t)(tc * 128 + rA0) * M1_ + m0 + cA0 * 16;
  const unsigned char* Bg1 = sT + (size_t)(tc * 128 + rA1) * M1_ + m0 + cA1 * 16;

  int4v acc[4][4] = {};
  const int clog = lane >> 4;

  gload_lds16(Ag0, smem + s0 * 16);
  gload_lds16(Ag1, smem + s1i * 16);
  gload_lds16(Bg0, smem + 8192 + s0 * 16);
  gload_lds16(Bg1, smem + 8192 + s1i * 16);
  __syncthreads();

  for (int kt = 0; kt < 32; ++kt) {
    if (kt < 31) {
      const int kn = (kt + 1) * 64;
      char* dst = smem + ((kt + 1) & 1) * 16384;
      gload_lds16(Ag0 + kn, dst + s0 * 16);
      gload_lds16(Ag1 + kn, dst + s1i * 16);
      gload_lds16(Bg0 + kn, dst + 8192 + s0 * 16);
      gload_lds16(Bg1 + kn, dst + 8192 + s1i * 16);
    }
    const signed char* ldsA = (const signed char*)smem + (kt & 1) * 16384;
    const signed char* ldsB = ldsA + 8192;
    int4v av[4], bv[4];
    #pragma unroll
    for (int m = 0; m < 4; ++m) {
      const int r = wr * 64 + m * 16 + (lane & 15);
      const int cp = clog ^ ((r >> 1) & 3);
      av[m] = *(const int4v*)(ldsA + r * 64 + cp * 16);
    }
    #pragma unroll
    for (int n = 0; n < 4; ++n) {
      const int r = wc * 64 + n * 16 + (lane & 15);
      const int cp = clog ^ ((r >> 1) & 3);
      bv[n] = *(const int4v*)(ldsB + r * 64 + cp * 16);
    }
    #pragma unroll
    for (int m = 0; m < 4; ++m)
      #pragma unroll
      for (int n = 0; n < 4; ++n)
        acc[m][n] = __builtin_amdgcn_mfma_i32_16x16x64_i8(av[m], bv[n], acc[m][n], 0, 0, 0);
    __syncthreads();
  }

  const int r0 = tr * 128 + wr * 64 + (clog << 2);
  const int c0 = tc * 128 + wc * 64 + (lane & 15);
  #pragma unroll
  for (int m = 0; m < 4; ++m)
    #pragma unroll
    for (int n = 0; n < 4; ++n)
      #pragma unroll
      for (int rr = 0; rr < 4; ++rr)
        Gpart[((size_t)ks * 768 + r0 + m * 16 + rr) * 768 + c0 + n * 16] = acc[m][n][rr];
}

// ---- reduce 8 Gram partials -> 2 i8 digit planes ----
__global__ __launch_bounds__(256) void k_gramred(const int* __restrict__ Gpart,
                                                 signed char* __restrict__ g0,
                                                 signed char* __restrict__ g1) {
  int i = blockIdx.x * 256 + threadIdx.x;
  if (i >= 768 * 768) return;
  int G = 0;
  #pragma unroll
  for (int ks = 0; ks < 8; ++ks) G += Gpart[(size_t)ks * 768 * 768 + i];
  int b0 = ((G + 128) & 255) - 128;
  g0[i] = (signed char)b0;
  g1[i] = (signed char)((G - b0) >> 8);
}

// ---- Y = G * Q (exact, fp64 fold), YT[c][k]. grid (12, 48) ----
__global__ __launch_bounds__(256, 2) void k_gq(
    const signed char* __restrict__ g0, const signed char* __restrict__ g1,
    const signed char* __restrict__ Q0, const signed char* __restrict__ Q1,
    const signed char* __restrict__ Q2, const signed char* __restrict__ Q3,
    double* __restrict__ YT) {
  __shared__ __align__(16) char smem[49152];
  const int tid = threadIdx.x;
  const int lane = tid & 63;
  const int w = tid >> 6;
  const int k0 = blockIdx.x * 64;
  const int c0 = blockIdx.y * 64;

  const int row = tid >> 2;
  const int ch = (tid & 3) ^ ((row >> 1) & 3);
  const signed char* Ag[2] = { g0 + (size_t)(k0 + row) * 768 + ch * 16,
                               g1 + (size_t)(k0 + row) * 768 + ch * 16 };
  const signed char* Bg[4] = { Q0 + (size_t)(c0 + row) * 768 + ch * 16,
                               Q1 + (size_t)(c0 + row) * 768 + ch * 16,
                               Q2 + (size_t)(c0 + row) * 768 + ch * 16,
                               Q3 + (size_t)(c0 + row) * 768 + ch * 16 };

  int4v acc[8][4] = {};
  const int clog = lane >> 4;

  #pragma unroll
  for (int a = 0; a < 2; ++a) gload_lds16(Ag[a], smem + a * 4096 + tid * 16);
  #pragma unroll
  for (int p = 0; p < 4; ++p) gload_lds16(Bg[p], smem + 8192 + p * 4096 + tid * 16);
  __syncthreads();

  for (int kt = 0; kt < 12; ++kt) {
    if (kt < 11) {
      const int kn = (kt + 1) * 64;
      char* dst = smem + ((kt + 1) & 1) * 24576;
      #pragma unroll
      for (int a = 0; a < 2; ++a) gload_lds16(Ag[a] + kn, dst + a * 4096 + tid * 16);
      #pragma unroll
      for (int p = 0; p < 4; ++p) gload_lds16(Bg[p] + kn, dst + 8192 + p * 4096 + tid * 16);
    }
    const signed char* base = (const signed char*)smem + (kt & 1) * 24576;
    const int ar = w * 16 + (lane & 15);
    const int acp = clog ^ ((ar >> 1) & 3);
    int4v av[2];
    #pragma unroll
    for (int a = 0; a < 2; ++a)
      av[a] = *(const int4v*)(base + a * 4096 + ar * 64 + acp * 16);
    #pragma unroll
    for (int p = 0; p < 4; ++p) {
      int4v bv[4];
      #pragma unroll
      for (int n = 0; n < 4; ++n) {
        const int br = n * 16 + (lane & 15);
        const int bcp = clog ^ ((br >> 1) & 3);
        bv[n] = *(const int4v*)(base + 8192 + p * 4096 + br * 64 + bcp * 16);
      }
      #pragma unroll
      for (int a = 0; a < 2; ++a)
        #pragma unroll
        for (int n = 0; n < 4; ++n)
          acc[a * 4 + p][n] = __builtin_amdgcn_mfma_i32_16x16x64_i8(av[a], bv[n], acc[a * 4 + p][n], 0, 0, 0);
    }
    __syncthreads();
  }

  #pragma unroll
  for (int n = 0; n < 4; ++n)
    #pragma unroll
    for (int r = 0; r < 4; ++r) {
      int A0 = acc[0][n][r] + (acc[4][n][r] << 8);
      int A1 = acc[1][n][r] + (acc[5][n][r] << 8);
      int A2 = acc[2][n][r] + (acc[6][n][r] << 8);
      int A3 = acc[3][n][r] + (acc[7][n][r] << 8);
      double Y = (double)A0 + 256.0 * (double)A1 + 65536.0 * (double)A2 + 16777216.0 * (double)A3;
      const int k = k0 + w * 16 + clog * 4 + r;
      const int c = c0 + n * 16 + (lane & 15);
      YT[(size_t)c * 768 + k] = Y;
    }
}

// ---- BN1 stats from Gram ----
__global__ __launch_bounds__(256) void k_stats1(
    const double* __restrict__ YT, const int* __restrict__ Qint,
    const int* __restrict__ colsum,
    double* __restrict__ mean, double* __restrict__ rstd) {
  __shared__ double red[8];
  const int c = blockIdx.x;
  const int tid = threadIdx.x;
  double s2 = 0.0, sm = 0.0;
  for (int k = tid; k < 768; k += 256) {
    double q = (double)Qint[(size_t)c * 768 + k];
    s2 += q * YT[(size_t)c * 768 + k];
    sm += q * (double)colsum[k];
  }
  #pragma unroll
  for (int o = 32; o; o >>= 1) { s2 += __shfl_xor(s2, o); sm += __shfl_xor(sm, o); }
  if ((tid & 63) == 0) { red[(tid >> 6) * 2] = s2; red[(tid >> 6) * 2 + 1] = sm; }
  __syncthreads();
  if (tid == 0) {
    double S2 = red[0] + red[2] + red[4] + red[6];
    double SM = red[1] + red[3] + red[5] + red[7];
    double mn = SM * INV33 * (1.0 / 16384.0);
    double Eh2 = S2 * INV33 * INV33 * (1.0 / 16384.0);
    double var = Eh2 - mn * mn;
    mean[c] = mn;
    rstd[c] = 1.0 / sqrt(var + 1e-5);
  }
}

// ---- GEMM1 + BN1-apply + fp64 LIF2 + transposed i8 spike write ----
// 3-buffer counted-vmcnt pipeline (T3+T4): stage k+2 while computing k.
// Per iter: stage -> vmcnt(12) -> barrier -> [SGB] reads+MFMA [SGB] -> barrier.
// SGB fences prevent the r5/r6 race (MFMA/ds_read migration across bare s_barrier).
__global__ __launch_bounds__(256, 2) void k_bnlif(
    const unsigned char* __restrict__ A,
    const signed char* __restrict__ Q0, const signed char* __restrict__ Q1,
    const signed char* __restrict__ Q2, const signed char* __restrict__ Q3,
    const double* __restrict__ mean, const double* __restrict__ rstd,
    const float* __restrict__ gamma, const float* __restrict__ beta,
    signed char* __restrict__ s2) {
  __shared__ __align__(16) char smem[73728];   // 3 x (A 8KB + B 16KB); epilogue overlays 48KB
  const int tid  = threadIdx.x;
  const int lane = tid & 63;
  const int w    = tid >> 6;
  const int wr = tid >> 7;
  const int wc = (tid >> 6) & 1;
  const int n0 = blockIdx.x * 64;
  const int by = blockIdx.y;

  auto grow = [&](int r) -> size_t {
    return (size_t)4096 * (r >> 5) + (size_t)by * 32 + (r & 31);
  };
  const int aIdx0 = w * 128 + lane;
  const int aIdx1 = aIdx0 + 64;
  const int ar0 = aIdx0 >> 2, ar1 = aIdx1 >> 2;
  const int ac0 = (aIdx0 & 3) ^ ((ar0 >> 1) & 3);
  const int ac1 = (aIdx1 & 3) ^ ((ar1 >> 1) & 3);
  const unsigned char* Ag0 = A + grow(ar0) * 768 + ac0 * 16;
  const unsigned char* Ag1 = A + grow(ar1) * 768 + ac1 * 16;
  const int bIdx = w * 64 + lane;
  const int brS = bIdx >> 2;
  const int bcS = (bIdx & 3) ^ ((brS >> 1) & 3);
  const signed char* Bg[4] = { Q0 + (size_t)(n0 + brS) * 768 + bcS * 16,
                               Q1 + (size_t)(n0 + brS) * 768 + bcS * 16,
                               Q2 + (size_t)(n0 + brS) * 768 + bcS * 16,
                               Q3 + (size_t)(n0 + brS) * 768 + bcS * 16 };

  int4v acc[4][4][2] = {};   // [plane][m][n]
  const int arow = wr * 64 + (lane & 15);
  const int clog = lane >> 4;

  auto stage = [&](int t) {
    char* dst = smem + (t % 3) * 24576;
    const int kn = t * 64;
    gload_lds16(Ag0 + kn, dst + aIdx0 * 16);
    gload_lds16(Ag1 + kn, dst + aIdx1 * 16);
    #pragma unroll
    for (int p = 0; p < 4; ++p) gload_lds16(Bg[p] + kn, dst + 8192 + p * 4096 + bIdx * 16);
  };

  stage(0);
  stage(1);
  for (int kt = 0; kt < 12; ++kt) {
    if (kt <= 9) stage(kt + 2);
    // counted wait: tiles kt+1, kt+2 may stay in flight (6 loads each)
    if (kt <= 9)       { asm volatile("s_waitcnt vmcnt(12)" ::: "memory"); }
    else if (kt == 10) { asm volatile("s_waitcnt vmcnt(6)" ::: "memory"); }
    else               { asm volatile("s_waitcnt vmcnt(0)" ::: "memory"); }
    SGB();
    HWBAR();           // all waves' tile-kt loads landed
    SGB();
    const signed char* ldsA = (const signed char*)smem + (kt % 3) * 24576;
    const signed char* ldsB = ldsA + 8192;
    int4v av[4], bv[2][4];
    #pragma unroll
    for (int m = 0; m < 4; ++m) {
      const int r = arow + m * 16;
      const int cp = clog ^ ((r >> 1) & 3);
      av[m] = *(const int4v*)(ldsA + r * 64 + cp * 16);
    }
    #pragma unroll
    for (int n = 0; n < 2; ++n) {
      const int r = wc * 32 + n * 16 + (lane & 15);
      const int cp = clog ^ ((r >> 1) & 3);
      #pragma unroll
      for (int p = 0; p < 4; ++p)
        bv[n][p] = *(const int4v*)(ldsB + p * 4096 + r * 64 + cp * 16);
    }
    #pragma unroll
    for (int p = 0; p < 4; ++p)
      #pragma unroll
      for (int m = 0; m < 4; ++m)
        #pragma unroll
        for (int n = 0; n < 2; ++n)
          acc[p][m][n] = __builtin_amdgcn_mfma_i32_16x16x64_i8(av[m], bv[n][p], acc[p][m][n], 0, 0, 0);
    SGB();
    HWBAR();           // close reads of buf[kt%3] before its reuse at kt+3
  }

  // exact h (48-bit) into LDS as lo32 + hi16 (cross-wave handoff via __syncthreads)
  unsigned int* smLo = (unsigned int*)smem;            // [128][64]
  short*        smHi = (short*)(smem + 32768);         // [128][64]
  #pragma unroll
  for (int m = 0; m < 4; ++m)
    #pragma unroll
    for (int n = 0; n < 2; ++n)
      #pragma unroll
      for (int r = 0; r < 4; ++r) {
        long long h = ((long long)acc[3][m][n][r] << 24) + ((long long)acc[2][m][n][r] << 16)
                    + ((long long)acc[1][m][n][r] << 8) + (long long)acc[0][m][n][r];
        const int rw = wr * 64 + m * 16 + clog * 4 + r;
        const int cl = wc * 32 + n * 16 + (lane & 15);
        smLo[rw * 64 + cl] = (unsigned int)h;
        smHi[rw * 64 + cl] = (short)(h >> 32);
      }
  __syncthreads();

  // fp64 LIF chains; col = tid&63 (bank-conflict-free), j = (tid>>6)*8 + jj
  const int col = tid & 63;
  const int jgrp = tid >> 6;
  const int c = n0 + col;
  const double mn = mean[c], rs = rstd[c];
  const double gm = (double)gamma[c], bt = (double)beta[c];
  const int bI = by >> 1;
  const int l0 = (by & 1) * 32;
  unsigned int plo[4] = {0, 0, 0, 0}, phi[4] = {0, 0, 0, 0};
  #pragma unroll
  for (int jj = 0; jj < 8; ++jj) {
    const int j = jgrp * 8 + jj;
    double v = 0.;
    #pragma unroll
    for (int t = 0; t < 4; ++t) {
      const int rw = t * 32 + j;
      long long h = ((long long)smHi[rw * 64 + col] << 32) | (unsigned long long)smLo[rw * 64 + col];
      double g = ((double)h * INV33 - mn) * rs * gm + bt;
      v = v + (g - v) * 0.5;
      bool s = (v >= 1.0);
      if (s) { if (jj < 4) plo[t] |= 1u << (8 * jj); else phi[t] |= 1u << (8 * (jj - 4)); }
      v = s ? 0. : v;
    }
  }
  #pragma unroll
  for (int t = 0; t < 4; ++t) {
    ui2 wv; wv.x = plo[t]; wv.y = phi[t];
    *(ui2*)(s2 + (size_t)(t * 64 + bI) * HL_ + (size_t)c * 64 + l0 + jgrp * 8) = wv;
  }
}

// ---- GEMM2: exact i8 x 2 planes, 3-buffer counted-vmcnt pipeline ----
__global__ __launch_bounds__(256, 2) void k_gemm2(
    const signed char* __restrict__ A,
    const signed char* __restrict__ R0, const signed char* __restrict__ R1,
    float* __restrict__ C,
    double* __restrict__ partS, double* __restrict__ partQ) {
  __shared__ __align__(16) char smem[73728];   // 3 x (A 8KB + P0 8KB + P1 8KB)
  const int tid  = threadIdx.x;
  const int lane = tid & 63;
  const int w    = tid >> 6;
  const int wr = tid >> 7;
  const int wc = (tid >> 6) & 1;
  const int n0 = blockIdx.x * 128;
  const int by = blockIdx.y;

  const int i0 = w * 128 + lane;
  const int i1 = i0 + 64;
  const int r0s = i0 >> 2, r1s = i1 >> 2;
  const int c0s = (i0 & 3) ^ ((r0s >> 1) & 3);
  const int c1s = (i1 & 3) ^ ((r1s >> 1) & 3);
  const signed char* Ag0 = A + (size_t)(by * 128 + r0s) * 3072 + c0s * 16;
  const signed char* Ag1 = A + (size_t)(by * 128 + r1s) * 3072 + c1s * 16;
  const signed char* P0g0 = R0 + (size_t)(n0 + r0s) * 3072 + c0s * 16;
  const signed char* P0g1 = R0 + (size_t)(n0 + r1s) * 3072 + c1s * 16;
  const signed char* P1g0 = R1 + (size_t)(n0 + r0s) * 3072 + c0s * 16;
  const signed char* P1g1 = R1 + (size_t)(n0 + r1s) * 3072 + c1s * 16;

  int4v acc[2][4][4] = {};
  const int arow = wr * 64 + (lane & 15);
  const int brow = wc * 64 + (lane & 15);
  const int clog = lane >> 4;

  auto stage = [&](int t) {
    char* dst = smem + (t % 3) * 24576;
    const int kn = t * 64;
    gload_lds16(Ag0 + kn, dst + i0 * 16);
    gload_lds16(Ag1 + kn, dst + i1 * 16);
    gload_lds16(P0g0 + kn, dst + 8192 + i0 * 16);
    gload_lds16(P0g1 + kn, dst + 8192 + i1 * 16);
    gload_lds16(P1g0 + kn, dst + 16384 + i0 * 16);
    gload_lds16(P1g1 + kn, dst + 16384 + i1 * 16);
  };

  stage(0);
  stage(1);
  for (int kt = 0; kt < 48; ++kt) {
    if (kt <= 45) stage(kt + 2);
    if (kt <= 45)      { asm volatile("s_waitcnt vmcnt(12)" ::: "memory"); }
    else if (kt == 46) { asm volatile("s_waitcnt vmcnt(6)" ::: "memory"); }
    else               { asm volatile("s_waitcnt vmcnt(0)" ::: "memory"); }
    SGB();
    HWBAR();
    SGB();
    const signed char* ldsA = (const signed char*)smem + (kt % 3) * 24576;
    int4v av[4], bv[2][4];
    #pragma unroll
    for (int m = 0; m < 4; ++m) {
      const int r = arow + m * 16;
      const int cp = clog ^ ((r >> 1) & 3);
      av[m] = *(const int4v*)(ldsA + r * 64 + cp * 16);
    }
    #pragma unroll
    for (int n = 0; n < 4; ++n) {
      const int r = brow + n * 16;
      const int cp = clog ^ ((r >> 1) & 3);
      bv[0][n] = *(const int4v*)(ldsA + 8192 + r * 64 + cp * 16);
      bv[1][n] = *(const int4v*)(ldsA + 16384 + r * 64 + cp * 16);
    }
    #pragma unroll
    for (int p = 0; p < 2; ++p)
      #pragma unroll
      for (int m = 0; m < 4; ++m)
        #pragma unroll
        for (int n = 0; n < 4; ++n)
          acc[p][m][n] = __builtin_amdgcn_mfma_i32_16x16x64_i8(av[m], bv[p][n], acc[p][m][n], 0, 0, 0);
    SGB();
    HWBAR();
  }

  const int r0o = by * 128 + wr * 64 + (clog << 2);
  const int c0o = n0 + wc * 64 + (lane & 15);
  #pragma unroll
  for (int n = 0; n < 4; ++n) {
    double s = 0.0, q = 0.0;
    #pragma unroll
    for (int m = 0; m < 4; ++m)
      #pragma unroll
      for (int r = 0; r < 4; ++r) {
        int hv = acc[0][m][n][r] + 256 * acc[1][m][n][r];
        double h = (double)hv * (1.0 / 131072.0);
        C[(size_t)(r0o + m * 16 + r) * 768 + (c0o + n * 16)] = (float)h;
        s += h;
        q += h * h;
      }
    s += __shfl_xor(s, 16);
    q += __shfl_xor(q, 16);
    s += __shfl_xor(s, 32);
    q += __shfl_xor(q, 32);
    if (clog == 0) {
      int col = n0 + wc * 64 + n * 16 + lane;
      partS[(size_t)(by * 2 + wr) * D_ + col] = s;
      partQ[(size_t)(by * 2 + wr) * D_ + col] = q;
    }
  }
}

// ---- reduce 256 partials -> mean, rstd (fp64) ----
__global__ __launch_bounds__(256) void k_bnred(
    const double* __restrict__ pS, const double* __restrict__ pQ,
    double* __restrict__ mean, double* __restrict__ rstd, int N, double invM) {
  int i = blockIdx.x * 256 + threadIdx.x;
  if (i >= N) return;
  double s = 0.0, q = 0.0;
  for (int p = 0; p < 256; ++p) {
    s += pS[(size_t)p * N + i];
    q += pQ[(size_t)p * N + i];
  }
  double m = s * invM;
  double v = q * invM - m * m;
  mean[i] = m;
  rstd[i] = 1.0 / sqrt(v + 1e-5);
}

// ---- BN2-apply (fp64) + (L,D)->(D,L) per-tb transpose -> fp32 out ----
__global__ __launch_bounds__(256) void k_bn2apply(
    const float* __restrict__ O, const double* __restrict__ mean,
    const double* __restrict__ rstd, const float* __restrict__ gamma,
    const float* __restrict__ beta, float* __restrict__ out) {
  __shared__ __align__(16) float sm[64 * 65];
  const int tid = threadIdx.x;
  const int d0 = blockIdx.x * 64;
  const int tb = blockIdx.y;
  const int doff = tid & 63;
  const int lgrp = tid >> 6;
  const double mn = mean[d0 + doff];
  const double rs = rstd[d0 + doff];
  const double gm = (double)gamma[d0 + doff];
  const double bt = (double)beta[d0 + doff];
  #pragma unroll 4
  for (int p = 0; p < 16; ++p) {
    const int l = p * 4 + lgrp;
    double v = (double)O[((size_t)tb * 64 + l) * D_ + d0 + doff];
    sm[doff * 65 + l] = (float)(((v - mn) * rs) * gm + bt);
  }
  __syncthreads();
  const int l4 = (tid & 15) * 4;
  const int db = tid >> 4;
  #pragma unroll
  for (int p = 0; p < 4; ++p) {
    const int dd = p * 16 + db;
    f4 wv;
    wv.x = sm[dd * 65 + l4 + 0];
    wv.y = sm[dd * 65 + l4 + 1];
    wv.z = sm[dd * 65 + l4 + 2];
    wv.w = sm[dd * 65 + l4 + 3];
    *(f4*)(out + (size_t)tb * (D_ * L_) + (size_t)(d0 + dd) * 64 + l4) = wv;
  }
}

extern "C" void kernel_launch(void* const* d_in, const int* in_sizes, int n_in,
                              void* d_out, int out_size, void* d_ws, size_t ws_size,
                              hipStream_t stream) {
  const float* x      = (const float*)d_in[0];
  const float* W1     = (const float*)d_in[1];
  const float* gamma1 = (const float*)d_in[2];
  const float* beta1  = (const float*)d_in[3];
  const float* W2     = (const float*)d_in[4];
  const float* gamma2 = (const float*)d_in[5];
  const float* beta2  = (const float*)d_in[6];
  float* out = (float*)d_out;
  (void)in_sizes; (void)n_in; (void)out_size; (void)ws_size;

  // s1 (i8 spikes, 12.6 MB) lives in d_out; d_out is fully rewritten at the end.
  unsigned char* s1 = (unsigned char*)d_out;

  char* ws = (char*)d_ws;
  size_t off = 0;
  auto alloc = [&](size_t bytes) -> void* {
    void* p = ws + off;
    off += (bytes + 255) & ~(size_t)255;
    return p;
  };
  signed char* Q0 = (signed char*)alloc(NW_);
  signed char* Q1 = (signed char*)alloc(NW_);
  signed char* Q2 = (signed char*)alloc(NW_);
  signed char* Q3 = (signed char*)alloc(NW_);
  int* Qint       = (int*)alloc((size_t)NW_ * 4);                 // 9.4 MB
  signed char* R0 = (signed char*)alloc(NW_);
  signed char* R1 = (signed char*)alloc(NW_);
  unsigned char* s1T = (unsigned char*)alloc((size_t)768 * M1_);  // 12.6 MB
  int* Gpart      = (int*)alloc((size_t)8 * 768 * 768 * 4);       // 18.9 MB
  signed char* g0 = (signed char*)alloc((size_t)768 * 768);
  signed char* g1 = (signed char*)alloc((size_t)768 * 768);
  double* YT      = (double*)alloc((size_t)H_ * 768 * 8);         // 18.9 MB
  int* colsum     = (int*)alloc(768 * 4);
  signed char* s2 = (signed char*)alloc((size_t)M1_ * H_);        // 50.3 MB
  float* O2       = (float*)alloc((size_t)M1_ * D_ * 4);          // 50.3 MB
  double* pS2 = (double*)alloc((size_t)256 * D_ * 8);
  double* pQ2 = (double*)alloc((size_t)256 * D_ * 8);
  double* mean1 = (double*)alloc((size_t)H_ * 8);
  double* rstd1 = (double*)alloc((size_t)H_ * 8);
  double* mean2 = (double*)alloc((size_t)D_ * 8);
  double* rstd2 = (double*)alloc((size_t)D_ * 8);

  hipMemsetAsync(colsum, 0, 768 * 4, stream);
  k_convert<<<NW_ / 256, 256, 0, stream>>>(W1, W2, Q0, Q1, Q2, Q3, Qint, R0, R1);
  k_lif1<<<BLD_ / 4 / 256, 256, 0, stream>>>(x, s1);
  k_s1t<<<dim3(12, 64, 4), 256, 0, stream>>>(s1, s1T, colsum);
  k_gram<<<dim3(36, 8), 256, 0, stream>>>(s1T, Gpart);
  k_gramred<<<(768 * 768) / 256, 256, 0, stream>>>(Gpart, g0, g1);
  k_gq<<<dim3(12, 48), 256, 0, stream>>>(g0, g1, Q0, Q1, Q2, Q3, YT);
  k_stats1<<<H_, 256, 0, stream>>>(YT, Qint, colsum, mean1, rstd1);
  k_bnlif<<<dim3(H_ / 64, (B_ * L_) / 32), 256, 0, stream>>>(
      s1, Q0, Q1, Q2, Q3, mean1, rstd1, gamma1, beta1, s2);
  k_gemm2<<<dim3(D_ / 128, M1_ / 128), 256, 0, stream>>>(s2, R0, R1, O2, pS2, pQ2);
  k_bnred<<<(D_ + 255) / 256, 256, 0, stream>>>(pS2, pQ2, mean2, rstd2, D_, 1.0 / (double)M1_);
  k_bn2apply<<<dim3(D_ / 64, T_ * B_), 256, 0, stream>>>(O2, mean2, rstd2, gamma2, beta2, out);
}